// Round 11
// baseline (362.613 us; speedup 1.0000x reference)
//
#include <hip/hip_runtime.h>
#include <math.h>

#define NEG_SLOPE 0.2f
#define GEPS 1e-5f

typedef __attribute__((ext_vector_type(8))) short short8;
typedef __attribute__((ext_vector_type(4))) float floatx4;

__device__ __forceinline__ float wave_reduce_sum(float v) {
#pragma unroll
    for (int o = 32; o > 0; o >>= 1) v += __shfl_down(v, o);
    return v;
}

__device__ __forceinline__ ushort f2bf(float f) {
    union { float f; unsigned int i; } c;
    c.f = f;
    unsigned int b = c.i;
    b += 0x7fffu + ((b >> 16) & 1u);
    return (ushort)(b >> 16);
}

__device__ __forceinline__ float bf2f(ushort u) {
    union { unsigned int i; float f; } c;
    c.i = (unsigned int)u << 16;
    return c.f;
}

__device__ __forceinline__ float2 unpack_bf2(unsigned int u) {
    union { unsigned int i; float f; } a, b;
    a.i = u << 16;            // low ushort -> even col
    b.i = u & 0xffff0000u;    // high ushort -> odd col
    return make_float2(a.f, b.f);
}

__device__ __forceinline__ unsigned int pack_bf2(float lo, float hi) {
    return (unsigned int)f2bf(lo) | ((unsigned int)f2bf(hi) << 16);
}

__device__ __forceinline__ float lrelu(float v) {
    return (v > 0.f) ? v : v * NEG_SLOPE;
}

// ---------------- edge_attr column sums + degree count (merged) ----------------
__global__ void k_ea_deg(const float* __restrict__ ea, const int* __restrict__ dst,
                         float* __restrict__ ea_sum, int* __restrict__ deg, int E) {
    const float2* ea2 = (const float2*)ea;
    float s0 = 0.f, s1 = 0.f;
    int stride = gridDim.x * blockDim.x;
    for (int e = blockIdx.x * blockDim.x + threadIdx.x; e < E; e += stride) {
        float2 v = ea2[e];
        s0 += v.x; s1 += v.y;
        atomicAdd(&deg[dst[e]], 1);
    }
    s0 = wave_reduce_sum(s0);
    s1 = wave_reduce_sum(s1);
    if ((threadIdx.x & 63) == 0) {
        atomicAdd(&ea_sum[0], s0);
        atomicAdd(&ea_sum[1], s1);
    }
}

// ---------------- CSR row_ptr scan (block-local) ----------------
__global__ void k_scan1(const int* __restrict__ deg, int* __restrict__ row_ptr,
                        int* __restrict__ bsum, int N) {
    __shared__ int tmp[1024];
    int tid = threadIdx.x;
    int i = blockIdx.x * 1024 + tid;
    int v = (i < N) ? deg[i] : 0;
    tmp[tid] = v;
    __syncthreads();
#pragma unroll
    for (int off = 1; off < 1024; off <<= 1) {
        int t = (tid >= off) ? tmp[tid - off] : 0;
        __syncthreads();
        tmp[tid] += t;
        __syncthreads();
    }
    if (i < N) row_ptr[i + 1] = tmp[tid];
    if (tid == 1023) bsum[blockIdx.x] = tmp[1023];
}

// block prefix recomputed per block in one wave (nb1 <= 64), then applied
__global__ void k_scan23(int* __restrict__ row_ptr, const int* __restrict__ bsum, int N) {
    __shared__ int off_s;
    int t = threadIdx.x;
    if (t < 64) {
        int v = (t < blockIdx.x) ? bsum[t] : 0;
#pragma unroll
        for (int o = 32; o > 0; o >>= 1) v += __shfl_xor(v, o);
        if (t == 0) off_s = v;
    }
    __syncthreads();
    int off = off_s;
    int i = blockIdx.x * 1024 + t;
    if (i == 0) row_ptr[0] = 0;
    if (i < N) row_ptr[i + 1] += off;
}

// ---------------- W2 -> bf16 MFMA B-fragment layout, + attn consts (block 16) ----------------
__global__ void k_w2frag(const float* __restrict__ W2, uint4* __restrict__ Bfrag,
                         const float* __restrict__ We1, const float* __restrict__ ae1,
                         const float* __restrict__ We2, const float* __restrict__ ae2,
                         const float* __restrict__ ea_sum, int E,
                         float* __restrict__ C1, float* __restrict__ lE1,
                         float* __restrict__ C2, float* __restrict__ lE2) {
    if (blockIdx.x == 16) {
        int t = threadIdx.x, h = t >> 6, lane = t & 63;
        float p0 = We1[t] * ae1[t];
        float p1 = We1[256 + t] * ae1[t];
        p0 = wave_reduce_sum(p0);
        p1 = wave_reduce_sum(p1);
        if (lane == 0) { C1[h] = p0; C1[4 + h] = p1; }
        if (t < 128) {
            float q0 = We2[t] * ae2[t];
            float q1 = We2[128 + t] * ae2[t];
            q0 = wave_reduce_sum(q0);
            q1 = wave_reduce_sum(q1);
            if (lane == 0) { C2[h] = q0; C2[2 + h] = q1; }
        }
        __syncthreads();
        float m0 = ea_sum[0] / (float)E, m1 = ea_sum[1] / (float)E;
        if (t < 4) lE1[t] = m0 * C1[t] + m1 * C1[4 + t];
        if (t < 2) lE2[t] = m0 * C2[t] + m1 * C2[2 + t];
        return;
    }
    int t = blockIdx.x * 256 + threadIdx.x;  // 4096 threads
    int c = t >> 9, kk = (t >> 6) & 7, L = t & 63;
    int q = L >> 4, n = c * 16 + (L & 15);
    int k0 = kk * 32 + q * 8;
    unsigned int u0 = pack_bf2(W2[(k0 + 0) * 128 + n], W2[(k0 + 1) * 128 + n]);
    unsigned int u1 = pack_bf2(W2[(k0 + 2) * 128 + n], W2[(k0 + 3) * 128 + n]);
    unsigned int u2 = pack_bf2(W2[(k0 + 4) * 128 + n], W2[(k0 + 5) * 128 + n]);
    unsigned int u3 = pack_bf2(W2[(k0 + 6) * 128 + n], W2[(k0 + 7) * 128 + n]);
    Bfrag[t] = make_uint4(u0, u1, u2, u3);
}

// ---------------- layer-1 transform: 2 nodes per 256-thread block ----------------
__global__ __launch_bounds__(256) void k_l1(const float* __restrict__ x,
                                            const float* __restrict__ W1,
                                            const float* __restrict__ as1,
                                            const float* __restrict__ ad1,
                                            ushort* __restrict__ h1, float* __restrict__ al_s,
                                            float* __restrict__ al_d, int N) {
    int u = threadIdx.x >> 7;
    int n = blockIdx.x * 2 + u;
    if (n >= N) return;
    int t = threadIdx.x & 127, lane = threadIdx.x & 63;
    int c0 = 2 * t;
    float x0 = x[3 * n], x1 = x[3 * n + 1], x2 = x[3 * n + 2];
    float h0 = fmaf(x0, W1[c0], fmaf(x1, W1[256 + c0], x2 * W1[512 + c0]));
    float h1v = fmaf(x0, W1[c0 + 1], fmaf(x1, W1[257 + c0], x2 * W1[513 + c0]));
    ((unsigned int*)h1)[(size_t)n * 128 + t] = pack_bf2(h0, h1v);
    float ps = h0 * as1[c0] + h1v * as1[c0 + 1];
    float pd = h0 * ad1[c0] + h1v * ad1[c0 + 1];
#pragma unroll
    for (int o = 16; o > 0; o >>= 1) {
        ps += __shfl_xor(ps, o);
        pd += __shfl_xor(pd, o);
    }
    if ((lane & 31) == 0) {
        int h = c0 >> 6;
        al_s[n * 4 + h] = ps;
        al_d[n * 4 + h] = pd;
    }
}

// ---------------- CSR scatter fused with layer-1 edge-weight computation ----------------
__global__ void k_scatfill(const int* __restrict__ dst, const int* __restrict__ src,
                           const float* __restrict__ ea, const int* __restrict__ row_ptr,
                           int* __restrict__ cursor, const float* __restrict__ al_s1,
                           const float* __restrict__ al_d1, const float* __restrict__ C1,
                           int* __restrict__ si, int* __restrict__ dstc,
                           float2* __restrict__ eacsr, uint4* __restrict__ wmp, int E) {
    int e = blockIdx.x * 256 + threadIdx.x;
    if (e >= E) return;
    int d = dst[e];
    int pos = atomicAdd(&cursor[d], 1);
    int slot = row_ptr[d] + pos;
    int s = src[e];
    float2 v = ((const float2*)ea)[e];
    float4 as = *(const float4*)(al_s1 + 4 * (size_t)s);
    float4 ad = *(const float4*)(al_d1 + 4 * (size_t)d);
    float w0 = __expf(lrelu(as.x + ad.x + v.x * C1[0] + v.y * C1[4]));
    float w1 = __expf(lrelu(as.y + ad.y + v.x * C1[1] + v.y * C1[5]));
    float w2 = __expf(lrelu(as.z + ad.z + v.x * C1[2] + v.y * C1[6]));
    float w3 = __expf(lrelu(as.w + ad.w + v.x * C1[3] + v.y * C1[7]));
    si[slot] = s;
    dstc[slot] = d;
    eacsr[slot] = v;
    wmp[slot] = make_uint4((unsigned int)s, pack_bf2(w0, w1), pack_bf2(w2, w3), 0u);
}

// ---------------- layer-2 edge-weight fill (CSR order) ----------------
__global__ void k_fill2(const int* __restrict__ si, const int* __restrict__ dstc,
                        const float2* __restrict__ eacsr, const float* __restrict__ al_s2,
                        const float* __restrict__ al_d2, const float* __restrict__ C2,
                        float4* __restrict__ wm2, int E) {
    int e = blockIdx.x * 256 + threadIdx.x;
    if (e >= E) return;
    int s = si[e], d = dstc[e];
    float2 v = eacsr[e];
    float2 as = *(const float2*)(al_s2 + 2 * (size_t)s);
    float2 ad = *(const float2*)(al_d2 + 2 * (size_t)d);
    float wA = __expf(lrelu(as.x + ad.x + v.x * C2[0] + v.y * C2[2]));
    float wB = __expf(lrelu(as.y + ad.y + v.x * C2[1] + v.y * C2[3]));
    wm2[e] = make_float4(__int_as_float(s), wA, wB, 0.f);
}

// ---------------- layer-1 aggregation: one wave per node, full 512B row ----------------
__global__ __launch_bounds__(256) void k_agg1(const ushort* __restrict__ h1,
                                              const int* __restrict__ row_ptr,
                                              const uint4* __restrict__ wmp,
                                              const float* __restrict__ al_s,
                                              const float* __restrict__ al_d,
                                              const float* __restrict__ lE,
                                              const float* __restrict__ bias,
                                              ushort* __restrict__ out, int N) {
    int n = blockIdx.x * 4 + (threadIdx.x >> 6);
    if (n >= N) return;
    int lane = threadIdx.x & 63;
    int g = lane >> 5, c32 = lane & 31;
    int h = c32 >> 3;
    const uint4* h1u4 = (const uint4*)h1;
    float4 as = *(const float4*)(al_s + 4 * (size_t)n);
    float4 ad = *(const float4*)(al_d + 4 * (size_t)n);
    float4 le = *(const float4*)lE;
    float ws0 = __expf(lrelu(as.x + ad.x + le.x));
    float ws1 = __expf(lrelu(as.y + ad.y + le.y));
    float ws2 = __expf(lrelu(as.z + ad.z + le.z));
    float ws3 = __expf(lrelu(as.w + ad.w + le.w));
    float wsh = (h == 0) ? ws0 : (h == 1) ? ws1 : (h == 2) ? ws2 : ws3;
    uint4 hs = h1u4[(size_t)n * 32 + c32];
    float wself = (g == 0) ? wsh : 0.f;
    float dsum = wself;
    float acc[8];
    {
        float2 t0 = unpack_bf2(hs.x), t1 = unpack_bf2(hs.y);
        float2 t2 = unpack_bf2(hs.z), t3 = unpack_bf2(hs.w);
        acc[0] = wself * t0.x; acc[1] = wself * t0.y;
        acc[2] = wself * t1.x; acc[3] = wself * t1.y;
        acc[4] = wself * t2.x; acc[5] = wself * t2.y;
        acc[6] = wself * t3.x; acc[7] = wself * t3.y;
    }
    int i0 = row_ptr[n];
    int cnt = row_ptr[n + 1] - i0;
    if (cnt > 0) {
        int last = cnt - 1;
        int j0 = g; float m0 = 1.f;
        if (j0 > last) { j0 = last; m0 = 0.f; }
        int j1 = 2 + g; float m1 = 1.f;
        if (j1 > last) { j1 = last; m1 = 0.f; }
        uint4 meA = wmp[i0 + j0];
        uint4 gvA = h1u4[(size_t)meA.x * 32 + c32];
        uint4 meB = wmp[i0 + j1];
        float mkA = m0, mkB = m1;
        int nit = (cnt + 1) >> 1;
        for (int it = 1; it < nit; ++it) {
            uint4 gvB = h1u4[(size_t)meB.x * 32 + c32];
            int jn = 2 * (it + 1) + g;
            float mn = 1.f;
            if (jn > last) { jn = last; mn = 0.f; }
            uint4 meC = wmp[i0 + jn];
            float2 w01 = unpack_bf2(meA.y);
            float2 w23 = unpack_bf2(meA.z);
            float2 wp = (h < 2) ? w01 : w23;
            float wg = ((h & 1) ? wp.y : wp.x) * mkA;
            dsum += wg;
            float2 u;
            u = unpack_bf2(gvA.x); acc[0] = fmaf(wg, u.x, acc[0]); acc[1] = fmaf(wg, u.y, acc[1]);
            u = unpack_bf2(gvA.y); acc[2] = fmaf(wg, u.x, acc[2]); acc[3] = fmaf(wg, u.y, acc[3]);
            u = unpack_bf2(gvA.z); acc[4] = fmaf(wg, u.x, acc[4]); acc[5] = fmaf(wg, u.y, acc[5]);
            u = unpack_bf2(gvA.w); acc[6] = fmaf(wg, u.x, acc[6]); acc[7] = fmaf(wg, u.y, acc[7]);
            meA = meB; gvA = gvB; meB = meC; mkA = mkB; mkB = mn;
        }
        float2 w01 = unpack_bf2(meA.y);
        float2 w23 = unpack_bf2(meA.z);
        float2 wp = (h < 2) ? w01 : w23;
        float wg = ((h & 1) ? wp.y : wp.x) * mkA;
        dsum += wg;
        float2 u;
        u = unpack_bf2(gvA.x); acc[0] = fmaf(wg, u.x, acc[0]); acc[1] = fmaf(wg, u.y, acc[1]);
        u = unpack_bf2(gvA.y); acc[2] = fmaf(wg, u.x, acc[2]); acc[3] = fmaf(wg, u.y, acc[3]);
        u = unpack_bf2(gvA.z); acc[4] = fmaf(wg, u.x, acc[4]); acc[5] = fmaf(wg, u.y, acc[5]);
        u = unpack_bf2(gvA.w); acc[6] = fmaf(wg, u.x, acc[6]); acc[7] = fmaf(wg, u.y, acc[7]);
    }
#pragma unroll
    for (int k = 0; k < 8; ++k) acc[k] += __shfl_xor(acc[k], 32);
    dsum += __shfl_xor(dsum, 32);
    if (g == 0) {
        float inv = 1.f / dsum;
        const float* bp = bias + c32 * 8;
        float4 b0 = *(const float4*)bp;
        float4 b1 = *(const float4*)(bp + 4);
        uint4 o;
        o.x = pack_bf2(fmaf(acc[0], inv, b0.x), fmaf(acc[1], inv, b0.y));
        o.y = pack_bf2(fmaf(acc[2], inv, b0.z), fmaf(acc[3], inv, b0.w));
        o.z = pack_bf2(fmaf(acc[4], inv, b1.x), fmaf(acc[5], inv, b1.y));
        o.w = pack_bf2(fmaf(acc[6], inv, b1.z), fmaf(acc[7], inv, b1.w));
        ((uint4*)out)[(size_t)n * 32 + c32] = o;
    }
}

// ---------------- layer-2 aggregation: 1 wave/node, 4 groups x 16 col-chunks ----------------
__global__ __launch_bounds__(256) void k_agg2(const ushort* __restrict__ h2,
                                              const int* __restrict__ row_ptr,
                                              const float4* __restrict__ wm,
                                              const float* __restrict__ al_s,
                                              const float* __restrict__ al_d,
                                              const float* __restrict__ lE,
                                              const float* __restrict__ bias,
                                              ushort* __restrict__ out, int N) {
    int n = blockIdx.x * 4 + (threadIdx.x >> 6);
    if (n >= N) return;
    int lane = threadIdx.x & 63;
    int g = lane >> 4, c16 = lane & 15;
    bool hi = c16 >= 8;
    const uint4* h2u4 = (const uint4*)h2;
    float2 ad = *(const float2*)(al_d + 2 * (size_t)n);
    float2 as = *(const float2*)(al_s + 2 * (size_t)n);
    float wsA = __expf(lrelu(as.x + ad.x + lE[0]));
    float wsB = __expf(lrelu(as.y + ad.y + lE[1]));
    uint4 hs = h2u4[(size_t)n * 16 + c16];
    float wself = (g == 0) ? (hi ? wsB : wsA) : 0.f;
    float dsum = wself;
    float acc[8];
    {
        float2 t0 = unpack_bf2(hs.x), t1 = unpack_bf2(hs.y);
        float2 t2 = unpack_bf2(hs.z), t3 = unpack_bf2(hs.w);
        acc[0] = wself * t0.x; acc[1] = wself * t0.y;
        acc[2] = wself * t1.x; acc[3] = wself * t1.y;
        acc[4] = wself * t2.x; acc[5] = wself * t2.y;
        acc[6] = wself * t3.x; acc[7] = wself * t3.y;
    }
    int i0 = row_ptr[n];
    int cnt = row_ptr[n + 1] - i0;
    if (cnt > 0) {
        int last = cnt - 1;
        int j0 = g; float m0 = 1.f;
        if (j0 > last) { j0 = last; m0 = 0.f; }
        int j1 = 4 + g; float m1 = 1.f;
        if (j1 > last) { j1 = last; m1 = 0.f; }
        float4 meA = wm[i0 + j0];
        uint4 gvA = h2u4[(size_t)__float_as_int(meA.x) * 16 + c16];
        float4 meB = wm[i0 + j1];
        float mkA = m0, mkB = m1;
        int nit = (cnt + 3) >> 2;
        for (int it = 1; it < nit; ++it) {
            uint4 gvB = h2u4[(size_t)__float_as_int(meB.x) * 16 + c16];
            int jn = 4 * (it + 1) + g;
            float mn = 1.f;
            if (jn > last) { jn = last; mn = 0.f; }
            float4 meC = wm[i0 + jn];
            float wg = (hi ? meA.z : meA.y) * mkA;
            dsum += wg;
            float2 u;
            u = unpack_bf2(gvA.x); acc[0] = fmaf(wg, u.x, acc[0]); acc[1] = fmaf(wg, u.y, acc[1]);
            u = unpack_bf2(gvA.y); acc[2] = fmaf(wg, u.x, acc[2]); acc[3] = fmaf(wg, u.y, acc[3]);
            u = unpack_bf2(gvA.z); acc[4] = fmaf(wg, u.x, acc[4]); acc[5] = fmaf(wg, u.y, acc[5]);
            u = unpack_bf2(gvA.w); acc[6] = fmaf(wg, u.x, acc[6]); acc[7] = fmaf(wg, u.y, acc[7]);
            meA = meB; gvA = gvB; meB = meC; mkA = mkB; mkB = mn;
        }
        float wg = (hi ? meA.z : meA.y) * mkA;
        dsum += wg;
        float2 u;
        u = unpack_bf2(gvA.x); acc[0] = fmaf(wg, u.x, acc[0]); acc[1] = fmaf(wg, u.y, acc[1]);
        u = unpack_bf2(gvA.y); acc[2] = fmaf(wg, u.x, acc[2]); acc[3] = fmaf(wg, u.y, acc[3]);
        u = unpack_bf2(gvA.z); acc[4] = fmaf(wg, u.x, acc[4]); acc[5] = fmaf(wg, u.y, acc[5]);
        u = unpack_bf2(gvA.w); acc[6] = fmaf(wg, u.x, acc[6]); acc[7] = fmaf(wg, u.y, acc[7]);
    }
#pragma unroll
    for (int k = 0; k < 8; ++k) {
        acc[k] += __shfl_xor(acc[k], 16);
        acc[k] += __shfl_xor(acc[k], 32);
    }
    dsum += __shfl_xor(dsum, 16);
    dsum += __shfl_xor(dsum, 32);
    if (g == 0) {
        float inv = 1.f / dsum;
        const float* bp = bias + c16 * 8;
        float4 b0 = *(const float4*)bp;
        float4 b1 = *(const float4*)(bp + 4);
        uint4 o;
        o.x = pack_bf2(fmaf(acc[0], inv, b0.x), fmaf(acc[1], inv, b0.y));
        o.y = pack_bf2(fmaf(acc[2], inv, b0.z), fmaf(acc[3], inv, b0.w));
        o.z = pack_bf2(fmaf(acc[4], inv, b1.x), fmaf(acc[5], inv, b1.y));
        o.w = pack_bf2(fmaf(acc[6], inv, b1.z), fmaf(acc[7], inv, b1.w));
        ((uint4*)out)[(size_t)n * 16 + c16] = o;
    }
}

// ---------------- GraphNorm stats + fused coef (last-block pattern) ----------------
template <int C4>
__global__ __launch_bounds__(256) void k_stats_bf(const ushort* __restrict__ x,
                                                  float* __restrict__ stats,
                                                  int* __restrict__ ctr,
                                                  const float* __restrict__ gw,
                                                  const float* __restrict__ gb,
                                                  const float* __restrict__ gms,
                                                  float* __restrict__ AB, int rows) {
    const int C = C4 * 8;
    const int RG = 256 / C4;
    int t = threadIdx.x;
    int c = t & (C4 - 1);
    int rg = t / C4;
    int rpb = (rows + gridDim.x - 1) / gridDim.x;
    int r0 = blockIdx.x * rpb;
    int r1 = r0 + rpb;
    if (r1 > rows) r1 = rows;
    const uint4* xu = (const uint4*)x;
    float s[8] = {0.f, 0.f, 0.f, 0.f, 0.f, 0.f, 0.f, 0.f};
    float q[8] = {0.f, 0.f, 0.f, 0.f, 0.f, 0.f, 0.f, 0.f};
    for (int r = r0 + rg; r < r1; r += RG) {
        uint4 v = xu[(size_t)r * C4 + c];
        float2 a0 = unpack_bf2(v.x), a1 = unpack_bf2(v.y);
        float2 a2 = unpack_bf2(v.z), a3 = unpack_bf2(v.w);
        s[0] += a0.x; q[0] = fmaf(a0.x, a0.x, q[0]);
        s[1] += a0.y; q[1] = fmaf(a0.y, a0.y, q[1]);
        s[2] += a1.x; q[2] = fmaf(a1.x, a1.x, q[2]);
        s[3] += a1.y; q[3] = fmaf(a1.y, a1.y, q[3]);
        s[4] += a2.x; q[4] = fmaf(a2.x, a2.x, q[4]);
        s[5] += a2.y; q[5] = fmaf(a2.y, a2.y, q[5]);
        s[6] += a3.x; q[6] = fmaf(a3.x, a3.x, q[6]);
        s[7] += a3.y; q[7] = fmaf(a3.y, a3.y, q[7]);
    }
    __shared__ float ls[256 * 16];
#pragma unroll
    for (int k = 0; k < 8; ++k) {
        ls[t * 16 + k] = s[k];
        ls[t * 16 + 8 + k] = q[k];
    }
    __syncthreads();
    if (t < C) {
        int cc = t >> 3, k = t & 7;
        float ssum = 0.f, qsum = 0.f;
#pragma unroll
        for (int g = 0; g < RG; ++g) {
            ssum += ls[(g * C4 + cc) * 16 + k];
            qsum += ls[(g * C4 + cc) * 16 + 8 + k];
        }
        atomicAdd(&stats[t], ssum);
        atomicAdd(&stats[C + t], qsum);
    }
    // last block computes AB
    __threadfence();
    __shared__ int isLast;
    if (t == 0) isLast = (atomicAdd(ctr, 1) == (int)gridDim.x - 1) ? 1 : 0;
    __syncthreads();
    if (isLast) {
        __threadfence();
        if (t < C) {
            float inv = 1.f / (float)rows;
            float mean = stats[t] * inv;
            float cm = mean * gms[t];
            float var = stats[C + t] * inv - 2.f * cm * mean + cm * cm;
            float A = gw[t] * rsqrtf(var + GEPS);
            AB[t] = A;
            AB[C + t] = gb[t] - A * cm;
        }
    }
}

// ---------------- MFMA GEMM2 + fused layer-2 attn dots ----------------
__global__ __launch_bounds__(256) void k_gemm2_mfma(const ushort* __restrict__ X,
                                                    const float* __restrict__ AB,
                                                    const uint4* __restrict__ Bfrag,
                                                    const float* __restrict__ as2,
                                                    const float* __restrict__ ad2,
                                                    ushort* __restrict__ H2,
                                                    float* __restrict__ al_s,
                                                    float* __restrict__ al_d, int Nn) {
    int wave = threadIdx.x >> 6, lane = threadIdx.x & 63;
    int q = lane >> 4, m = lane & 15;
    int rowbase = blockIdx.x * 64 + wave * 16;
    int row = rowbase + m;
    bool valid = row < Nn;
    floatx4 acc[8];
#pragma unroll
    for (int c = 0; c < 8; ++c) acc[c] = (floatx4){0.f, 0.f, 0.f, 0.f};
    const uint4* xr4 = (const uint4*)((const unsigned int*)X + (size_t)row * 128);
#pragma unroll
    for (int kk = 0; kk < 8; ++kk) {
        int k0 = kk * 32 + q * 8;
        uint4 xu = valid ? xr4[k0 >> 3] : make_uint4(0, 0, 0, 0);
        float2 x01 = unpack_bf2(xu.x);
        float2 x23 = unpack_bf2(xu.y);
        float2 x45 = unpack_bf2(xu.z);
        float2 x67 = unpack_bf2(xu.w);
        float4 a0 = *(const float4*)(AB + k0);
        float4 a1 = *(const float4*)(AB + k0 + 4);
        float4 b0 = *(const float4*)(AB + 256 + k0);
        float4 b1 = *(const float4*)(AB + 256 + k0 + 4);
        float v0 = fmaf(a0.x, x01.x, b0.x);
        float v1 = fmaf(a0.y, x01.y, b0.y);
        float v2 = fmaf(a0.z, x23.x, b0.z);
        float v3 = fmaf(a0.w, x23.y, b0.w);
        float v4 = fmaf(a1.x, x45.x, b1.x);
        float v5 = fmaf(a1.y, x45.y, b1.y);
        float v6 = fmaf(a1.z, x67.x, b1.z);
        float v7 = fmaf(a1.w, x67.y, b1.w);
        v0 = (v0 > 0.f) ? v0 : expm1f(v0);
        v1 = (v1 > 0.f) ? v1 : expm1f(v1);
        v2 = (v2 > 0.f) ? v2 : expm1f(v2);
        v3 = (v3 > 0.f) ? v3 : expm1f(v3);
        v4 = (v4 > 0.f) ? v4 : expm1f(v4);
        v5 = (v5 > 0.f) ? v5 : expm1f(v5);
        v6 = (v6 > 0.f) ? v6 : expm1f(v6);
        v7 = (v7 > 0.f) ? v7 : expm1f(v7);
        union { short8 s; unsigned int u[4]; } af;
        af.u[0] = pack_bf2(v0, v1);
        af.u[1] = pack_bf2(v2, v3);
        af.u[2] = pack_bf2(v4, v5);
        af.u[3] = pack_bf2(v6, v7);
        const uint4* bp = Bfrag + kk * 64 + lane;
#pragma unroll
        for (int c = 0; c < 8; ++c) {
            union { short8 s; uint4 u; } bf;
            bf.u = bp[c * 8 * 64];
            acc[c] = __builtin_amdgcn_mfma_f32_16x16x32_bf16(af.s, bf.s, acc[c], 0, 0, 0);
        }
    }
    float a_s[8], a_d[8];
#pragma unroll
    for (int c = 0; c < 8; ++c) {
        a_s[c] = as2[c * 16 + m];
        a_d[c] = ad2[c * 16 + m];
    }
#pragma unroll
    for (int r = 0; r < 4; ++r) {
        int orow = rowbase + q * 4 + r;
        bool vr = orow < Nn;
        ushort us[8];
        float s0 = 0.f, s1 = 0.f, d0 = 0.f, d1 = 0.f;
#pragma unroll
        for (int c = 0; c < 8; ++c) {
            us[c] = f2bf(acc[c][r]);
            float v = bf2f(us[c]);
            if (c < 4) {
                s0 = fmaf(v, a_s[c], s0);
                d0 = fmaf(v, a_d[c], d0);
            } else {
                s1 = fmaf(v, a_s[c], s1);
                d1 = fmaf(v, a_d[c], d1);
            }
        }
#pragma unroll
        for (int o = 1; o < 16; o <<= 1) {
            s0 += __shfl_xor(s0, o);
            s1 += __shfl_xor(s1, o);
            d0 += __shfl_xor(d0, o);
            d1 += __shfl_xor(d1, o);
        }
        if (vr) {
            ushort* op = H2 + (size_t)orow * 128 + m;
#pragma unroll
            for (int c = 0; c < 8; ++c) op[c * 16] = us[c];
            if (m == 0) {
                *(float2*)(al_s + 2 * (size_t)orow) = make_float2(s0, s1);
                *(float2*)(al_d + 2 * (size_t)orow) = make_float2(d0, d1);
            }
        }
    }
}

// ---------------- classifier with fused GraphNorm+ELU, bf16 input ----------------
__global__ __launch_bounds__(256) void k_cls(const ushort* __restrict__ X,
                                             const float* __restrict__ AB,
                                             const float* __restrict__ Wc,
                                             const float* __restrict__ bc,
                                             float* __restrict__ out, int Nn) {
    __shared__ __align__(16) float ls[16 * 132];
    __shared__ __align__(16) float wT[13 * 132];
    __shared__ float bS[13];
    int t = threadIdx.x;
    int n0 = blockIdx.x * 16;
    for (int i = t; i < 128 * 13; i += 256) {
        int k = i / 13, j = i - k * 13;
        wT[j * 132 + k] = Wc[i];
    }
    if (t < 13) bS[t] = bc[t];
    const unsigned int* xu = (const unsigned int*)X;
    for (int idx = t; idx < 16 * 64; idx += 256) {
        int r = idx >> 6, ku = idx & 63;
        int row = n0 + r;
        float vx = 0.f, vy = 0.f;
        if (row < Nn) {
            float2 v = unpack_bf2(xu[(size_t)row * 64 + ku]);
            int k = 2 * ku;
            vx = fmaf(AB[k], v.x, AB[128 + k]);
            vy = fmaf(AB[k + 1], v.y, AB[128 + k + 1]);
            vx = (vx > 0.f) ? vx : expm1f(vx);
            vy = (vy > 0.f) ? vy : expm1f(vy);
        }
        ls[r * 132 + 2 * ku] = vx;
        ls[r * 132 + 2 * ku + 1] = vy;
    }
    __syncthreads();
    if (t < 208) {
        int r = t / 13, j = t - r * 13;
        int row = n0 + r;
        if (row < Nn) {
            float acc = bS[j];
            const float* lr = &ls[r * 132];
            const float* wr = &wT[j * 132];
#pragma unroll 8
            for (int k = 0; k < 128; k += 4) {
                float4 a = *(const float4*)&lr[k];
                float4 b = *(const float4*)&wr[k];
                acc = fmaf(a.x, b.x, fmaf(a.y, b.y, fmaf(a.z, b.z, fmaf(a.w, b.w, acc))));
            }
            out[(size_t)row * 13 + j] = acc;
        }
    }
}

extern "C" void kernel_launch(void* const* d_in, const int* in_sizes, int n_in, void* d_out,
                              int out_size, void* d_ws, size_t ws_size, hipStream_t stream) {
    const float* x = (const float*)d_in[0];
    const int* edge_index = (const int*)d_in[1];
    const float* edge_attr = (const float*)d_in[2];
    const float* W1 = (const float*)d_in[3];
    const float* We1 = (const float*)d_in[4];
    const float* as1 = (const float*)d_in[5];
    const float* ad1 = (const float*)d_in[6];
    const float* ae1 = (const float*)d_in[7];
    const float* b1 = (const float*)d_in[8];
    const float* gn1_w = (const float*)d_in[9];
    const float* gn1_b = (const float*)d_in[10];
    const float* gn1_ms = (const float*)d_in[11];
    const float* W2 = (const float*)d_in[12];
    const float* We2 = (const float*)d_in[13];
    const float* as2 = (const float*)d_in[14];
    const float* ad2 = (const float*)d_in[15];
    const float* ae2 = (const float*)d_in[16];
    const float* b2 = (const float*)d_in[17];
    const float* gn2_w = (const float*)d_in[18];
    const float* gn2_b = (const float*)d_in[19];
    const float* gn2_ms = (const float*)d_in[20];
    const float* Wc = (const float*)d_in[21];
    const float* bc = (const float*)d_in[22];

    const int N = in_sizes[0] / 3;
    const int E = in_sizes[1] / 2;
    const int* srcv = edge_index;
    const int* dstv = edge_index + E;

    // ---- workspace carve (256B-aligned, byte-based) ----
    char* w = (char*)d_ws;
    auto carveB = [&](size_t bytes) -> void* {
        void* p = (void*)w;
        w += ((bytes + 255) / 256) * 256;
        return p;
    };
    // zeroed region first:
    int* deg = (int*)carveB((size_t)N * 4);
    int* cursor = (int*)carveB((size_t)N * 4);
    float* ea_sum = (float*)carveB(8);
    float* statsA = (float*)carveB(512 * 4);
    float* statsB = (float*)carveB(256 * 4);
    int* ctrA = (int*)carveB(8);
    int* ctrB = (int*)carveB(8);
    char* zero_end = w;
    // not zeroed:
    int* row_ptr = (int*)carveB((size_t)(N + 1) * 4);
    int* bsum = (int*)carveB(1024 * 4);
    int* si = (int*)carveB((size_t)E * 4);
    int* dstc = (int*)carveB((size_t)E * 4);
    float2* eacsr = (float2*)carveB((size_t)E * 8);
    uint4* wmp = (uint4*)carveB((size_t)E * 16);
    float4* wm2 = (float4*)wmp;  // layer-2 weights reuse (wmp dead after agg1)
    float* C1 = (float*)carveB(8 * 4);
    float* lE1 = (float*)carveB(4 * 4);
    float* C2 = (float*)carveB(4 * 4);
    float* lE2 = (float*)carveB(2 * 4);
    float* AB1 = (float*)carveB(512 * 4);
    float* AB2 = (float*)carveB(256 * 4);
    uint4* Bfrag = (uint4*)carveB(4096 * 16);
    float* al_s1 = (float*)carveB((size_t)N * 4 * 4);
    float* al_d1 = (float*)carveB((size_t)N * 4 * 4);
    float* al_s2 = (float*)carveB((size_t)N * 2 * 4);
    float* al_d2 = (float*)carveB((size_t)N * 2 * 4);
    ushort* h1b = (ushort*)carveB((size_t)N * 256 * 2);   // bf16 h1; later aliased by out2b
    ushort* h2b = (ushort*)carveB((size_t)N * 128 * 2);   // bf16 h2
    ushort* out1b = (ushort*)carveB((size_t)N * 256 * 2); // bf16 layer-1 output
    ushort* out2b = h1b;                                  // bf16 layer-2 output (h1b dead)

    hipMemsetAsync(deg, 0, (size_t)(zero_end - (char*)deg), stream);

    const int nb1 = (N + 1023) / 1024;
    const int ebl = (E + 255) / 256;

    k_ea_deg<<<256, 256, 0, stream>>>(edge_attr, dstv, ea_sum, deg, E);
    k_scan1<<<nb1, 1024, 0, stream>>>(deg, row_ptr, bsum, N);
    k_scan23<<<nb1, 1024, 0, stream>>>(row_ptr, bsum, N);
    k_w2frag<<<17, 256, 0, stream>>>(W2, Bfrag, We1, ae1, We2, ae2, ea_sum, E, C1, lE1, C2, lE2);

    // ---- layer 1 ----
    k_l1<<<(N + 1) / 2, 256, 0, stream>>>(x, W1, as1, ad1, h1b, al_s1, al_d1, N);
    k_scatfill<<<ebl, 256, 0, stream>>>(dstv, srcv, edge_attr, row_ptr, cursor, al_s1, al_d1, C1,
                                        si, dstc, eacsr, wmp, E);
    k_agg1<<<(N + 3) / 4, 256, 0, stream>>>(h1b, row_ptr, wmp, al_s1, al_d1, lE1, b1, out1b, N);
    k_stats_bf<32><<<256, 256, 0, stream>>>(out1b, statsA, ctrA, gn1_w, gn1_b, gn1_ms, AB1, N);

    // ---- layer 2 (norm+ELU fused into MFMA GEMM A-load; attn dots fused in epilogue) ----
    k_gemm2_mfma<<<(N + 63) / 64, 256, 0, stream>>>(out1b, AB1, Bfrag, as2, ad2, h2b, al_s2,
                                                    al_d2, N);
    k_fill2<<<ebl, 256, 0, stream>>>(si, dstc, eacsr, al_s2, al_d2, C2, wm2, E);
    k_agg2<<<(N + 3) / 4, 256, 0, stream>>>(h2b, row_ptr, wm2, al_s2, al_d2, lE2, b2, out2b, N);
    k_stats_bf<16><<<256, 256, 0, stream>>>(out2b, statsB, ctrB, gn2_w, gn2_b, gn2_ms, AB2, N);

    // ---- classifier (norm+ELU fused) ----
    k_cls<<<(N + 15) / 16, 256, 0, stream>>>(out2b, AB2, Wc, bc, (float*)d_out, N);
}

// Round 12
// 344.420 us; speedup vs baseline: 1.0528x; 1.0528x over previous
//
#include <hip/hip_runtime.h>
#include <math.h>

#define NEG_SLOPE 0.2f
#define GEPS 1e-5f

typedef __attribute__((ext_vector_type(8))) short short8;
typedef __attribute__((ext_vector_type(4))) float floatx4;

__device__ __forceinline__ float wave_reduce_sum(float v) {
#pragma unroll
    for (int o = 32; o > 0; o >>= 1) v += __shfl_down(v, o);
    return v;
}

__device__ __forceinline__ ushort f2bf(float f) {
    union { float f; unsigned int i; } c;
    c.f = f;
    unsigned int b = c.i;
    b += 0x7fffu + ((b >> 16) & 1u);
    return (ushort)(b >> 16);
}

__device__ __forceinline__ float bf2f(ushort u) {
    union { unsigned int i; float f; } c;
    c.i = (unsigned int)u << 16;
    return c.f;
}

__device__ __forceinline__ float2 unpack_bf2(unsigned int u) {
    union { unsigned int i; float f; } a, b;
    a.i = u << 16;            // low ushort -> even col
    b.i = u & 0xffff0000u;    // high ushort -> odd col
    return make_float2(a.f, b.f);
}

__device__ __forceinline__ unsigned int pack_bf2(float lo, float hi) {
    return (unsigned int)f2bf(lo) | ((unsigned int)f2bf(hi) << 16);
}

__device__ __forceinline__ float lrelu(float v) {
    return (v > 0.f) ? v : v * NEG_SLOPE;
}

// ---------------- edge_attr column sums + degree count (merged) ----------------
__global__ void k_ea_deg(const float* __restrict__ ea, const int* __restrict__ dst,
                         float* __restrict__ ea_sum, int* __restrict__ deg, int E) {
    const float2* ea2 = (const float2*)ea;
    float s0 = 0.f, s1 = 0.f;
    int stride = gridDim.x * blockDim.x;
    for (int e = blockIdx.x * blockDim.x + threadIdx.x; e < E; e += stride) {
        float2 v = ea2[e];
        s0 += v.x; s1 += v.y;
        atomicAdd(&deg[dst[e]], 1);
    }
    s0 = wave_reduce_sum(s0);
    s1 = wave_reduce_sum(s1);
    if ((threadIdx.x & 63) == 0) {
        atomicAdd(&ea_sum[0], s0);
        atomicAdd(&ea_sum[1], s1);
    }
}

// ---------------- CSR row_ptr scan (block-local) ----------------
__global__ void k_scan1(const int* __restrict__ deg, int* __restrict__ row_ptr,
                        int* __restrict__ bsum, int N) {
    __shared__ int tmp[1024];
    int tid = threadIdx.x;
    int i = blockIdx.x * 1024 + tid;
    int v = (i < N) ? deg[i] : 0;
    tmp[tid] = v;
    __syncthreads();
#pragma unroll
    for (int off = 1; off < 1024; off <<= 1) {
        int t = (tid >= off) ? tmp[tid - off] : 0;
        __syncthreads();
        tmp[tid] += t;
        __syncthreads();
    }
    if (i < N) row_ptr[i + 1] = tmp[tid];
    if (tid == 1023) bsum[blockIdx.x] = tmp[1023];
}

// block prefix recomputed per block in one wave (nb1 <= 64), then applied
__global__ void k_scan23(int* __restrict__ row_ptr, const int* __restrict__ bsum, int N) {
    __shared__ int off_s;
    int t = threadIdx.x;
    if (t < 64) {
        int v = (t < blockIdx.x) ? bsum[t] : 0;
#pragma unroll
        for (int o = 32; o > 0; o >>= 1) v += __shfl_xor(v, o);
        if (t == 0) off_s = v;
    }
    __syncthreads();
    int off = off_s;
    int i = blockIdx.x * 1024 + t;
    if (i == 0) row_ptr[0] = 0;
    if (i < N) row_ptr[i + 1] += off;
}

// ---------------- W2 -> bf16 MFMA B-fragment layout, + attn consts (block 16) ----------------
__global__ void k_w2frag(const float* __restrict__ W2, uint4* __restrict__ Bfrag,
                         const float* __restrict__ We1, const float* __restrict__ ae1,
                         const float* __restrict__ We2, const float* __restrict__ ae2,
                         const float* __restrict__ ea_sum, int E,
                         float* __restrict__ C1, float* __restrict__ lE1,
                         float* __restrict__ C2, float* __restrict__ lE2) {
    if (blockIdx.x == 16) {
        int t = threadIdx.x, h = t >> 6, lane = t & 63;
        float p0 = We1[t] * ae1[t];
        float p1 = We1[256 + t] * ae1[t];
        p0 = wave_reduce_sum(p0);
        p1 = wave_reduce_sum(p1);
        if (lane == 0) { C1[h] = p0; C1[4 + h] = p1; }
        if (t < 128) {
            float q0 = We2[t] * ae2[t];
            float q1 = We2[128 + t] * ae2[t];
            q0 = wave_reduce_sum(q0);
            q1 = wave_reduce_sum(q1);
            if (lane == 0) { C2[h] = q0; C2[2 + h] = q1; }
        }
        __syncthreads();
        float m0 = ea_sum[0] / (float)E, m1 = ea_sum[1] / (float)E;
        if (t < 4) lE1[t] = m0 * C1[t] + m1 * C1[4 + t];
        if (t < 2) lE2[t] = m0 * C2[t] + m1 * C2[2 + t];
        return;
    }
    int t = blockIdx.x * 256 + threadIdx.x;  // 4096 threads
    int c = t >> 9, kk = (t >> 6) & 7, L = t & 63;
    int q = L >> 4, n = c * 16 + (L & 15);
    int k0 = kk * 32 + q * 8;
    unsigned int u0 = pack_bf2(W2[(k0 + 0) * 128 + n], W2[(k0 + 1) * 128 + n]);
    unsigned int u1 = pack_bf2(W2[(k0 + 2) * 128 + n], W2[(k0 + 3) * 128 + n]);
    unsigned int u2 = pack_bf2(W2[(k0 + 4) * 128 + n], W2[(k0 + 5) * 128 + n]);
    unsigned int u3 = pack_bf2(W2[(k0 + 6) * 128 + n], W2[(k0 + 7) * 128 + n]);
    Bfrag[t] = make_uint4(u0, u1, u2, u3);
}

// ---------------- layer-1 transform: 2 nodes per 256-thread block ----------------
__global__ __launch_bounds__(256) void k_l1(const float* __restrict__ x,
                                            const float* __restrict__ W1,
                                            const float* __restrict__ as1,
                                            const float* __restrict__ ad1,
                                            ushort* __restrict__ h1, float* __restrict__ al_s,
                                            float* __restrict__ al_d, int N) {
    int u = threadIdx.x >> 7;
    int n = blockIdx.x * 2 + u;
    if (n >= N) return;
    int t = threadIdx.x & 127, lane = threadIdx.x & 63;
    int c0 = 2 * t;
    float x0 = x[3 * n], x1 = x[3 * n + 1], x2 = x[3 * n + 2];
    float h0 = fmaf(x0, W1[c0], fmaf(x1, W1[256 + c0], x2 * W1[512 + c0]));
    float h1v = fmaf(x0, W1[c0 + 1], fmaf(x1, W1[257 + c0], x2 * W1[513 + c0]));
    ((unsigned int*)h1)[(size_t)n * 128 + t] = pack_bf2(h0, h1v);
    float ps = h0 * as1[c0] + h1v * as1[c0 + 1];
    float pd = h0 * ad1[c0] + h1v * ad1[c0 + 1];
#pragma unroll
    for (int o = 16; o > 0; o >>= 1) {
        ps += __shfl_xor(ps, o);
        pd += __shfl_xor(pd, o);
    }
    if ((lane & 31) == 0) {
        int h = c0 >> 6;
        al_s[n * 4 + h] = ps;
        al_d[n * 4 + h] = pd;
    }
}

// ---------------- CSR scatter fused with layer-1 edge-weight computation ----------------
__global__ void k_scatfill(const int* __restrict__ dst, const int* __restrict__ src,
                           const float* __restrict__ ea, const int* __restrict__ row_ptr,
                           int* __restrict__ cursor, const float* __restrict__ al_s1,
                           const float* __restrict__ al_d1, const float* __restrict__ C1,
                           int* __restrict__ si, int* __restrict__ dstc,
                           float2* __restrict__ eacsr, uint4* __restrict__ wmp, int E) {
    int e = blockIdx.x * 256 + threadIdx.x;
    if (e >= E) return;
    int d = dst[e];
    int pos = atomicAdd(&cursor[d], 1);
    int slot = row_ptr[d] + pos;
    int s = src[e];
    float2 v = ((const float2*)ea)[e];
    float4 as = *(const float4*)(al_s1 + 4 * (size_t)s);
    float4 ad = *(const float4*)(al_d1 + 4 * (size_t)d);
    float w0 = __expf(lrelu(as.x + ad.x + v.x * C1[0] + v.y * C1[4]));
    float w1 = __expf(lrelu(as.y + ad.y + v.x * C1[1] + v.y * C1[5]));
    float w2 = __expf(lrelu(as.z + ad.z + v.x * C1[2] + v.y * C1[6]));
    float w3 = __expf(lrelu(as.w + ad.w + v.x * C1[3] + v.y * C1[7]));
    si[slot] = s;
    dstc[slot] = d;
    eacsr[slot] = v;
    wmp[slot] = make_uint4((unsigned int)s, pack_bf2(w0, w1), pack_bf2(w2, w3), 0u);
}

// ---------------- layer-2 edge-weight fill (CSR order) ----------------
__global__ void k_fill2(const int* __restrict__ si, const int* __restrict__ dstc,
                        const float2* __restrict__ eacsr, const float* __restrict__ al_s2,
                        const float* __restrict__ al_d2, const float* __restrict__ C2,
                        float4* __restrict__ wm2, int E) {
    int e = blockIdx.x * 256 + threadIdx.x;
    if (e >= E) return;
    int s = si[e], d = dstc[e];
    float2 v = eacsr[e];
    float2 as = *(const float2*)(al_s2 + 2 * (size_t)s);
    float2 ad = *(const float2*)(al_d2 + 2 * (size_t)d);
    float wA = __expf(lrelu(as.x + ad.x + v.x * C2[0] + v.y * C2[2]));
    float wB = __expf(lrelu(as.y + ad.y + v.x * C2[1] + v.y * C2[3]));
    wm2[e] = make_float4(__int_as_float(s), wA, wB, 0.f);
}

// ---------------- layer-1 aggregation: one wave per node, full 512B row ----------------
__global__ __launch_bounds__(256) void k_agg1(const ushort* __restrict__ h1,
                                              const int* __restrict__ row_ptr,
                                              const uint4* __restrict__ wmp,
                                              const float* __restrict__ al_s,
                                              const float* __restrict__ al_d,
                                              const float* __restrict__ lE,
                                              const float* __restrict__ bias,
                                              ushort* __restrict__ out, int N) {
    int n = blockIdx.x * 4 + (threadIdx.x >> 6);
    if (n >= N) return;
    int lane = threadIdx.x & 63;
    int g = lane >> 5, c32 = lane & 31;
    int h = c32 >> 3;
    const uint4* h1u4 = (const uint4*)h1;
    float4 as = *(const float4*)(al_s + 4 * (size_t)n);
    float4 ad = *(const float4*)(al_d + 4 * (size_t)n);
    float4 le = *(const float4*)lE;
    float ws0 = __expf(lrelu(as.x + ad.x + le.x));
    float ws1 = __expf(lrelu(as.y + ad.y + le.y));
    float ws2 = __expf(lrelu(as.z + ad.z + le.z));
    float ws3 = __expf(lrelu(as.w + ad.w + le.w));
    float wsh = (h == 0) ? ws0 : (h == 1) ? ws1 : (h == 2) ? ws2 : ws3;
    uint4 hs = h1u4[(size_t)n * 32 + c32];
    float wself = (g == 0) ? wsh : 0.f;
    float dsum = wself;
    float acc[8];
    {
        float2 t0 = unpack_bf2(hs.x), t1 = unpack_bf2(hs.y);
        float2 t2 = unpack_bf2(hs.z), t3 = unpack_bf2(hs.w);
        acc[0] = wself * t0.x; acc[1] = wself * t0.y;
        acc[2] = wself * t1.x; acc[3] = wself * t1.y;
        acc[4] = wself * t2.x; acc[5] = wself * t2.y;
        acc[6] = wself * t3.x; acc[7] = wself * t3.y;
    }
    int i0 = row_ptr[n];
    int cnt = row_ptr[n + 1] - i0;
    if (cnt > 0) {
        int last = cnt - 1;
        int j0 = g; float m0 = 1.f;
        if (j0 > last) { j0 = last; m0 = 0.f; }
        int j1 = 2 + g; float m1 = 1.f;
        if (j1 > last) { j1 = last; m1 = 0.f; }
        uint4 meA = wmp[i0 + j0];
        uint4 gvA = h1u4[(size_t)meA.x * 32 + c32];
        uint4 meB = wmp[i0 + j1];
        float mkA = m0, mkB = m1;
        int nit = (cnt + 1) >> 1;
        for (int it = 1; it < nit; ++it) {
            uint4 gvB = h1u4[(size_t)meB.x * 32 + c32];
            int jn = 2 * (it + 1) + g;
            float mn = 1.f;
            if (jn > last) { jn = last; mn = 0.f; }
            uint4 meC = wmp[i0 + jn];
            float2 w01 = unpack_bf2(meA.y);
            float2 w23 = unpack_bf2(meA.z);
            float2 wp = (h < 2) ? w01 : w23;
            float wg = ((h & 1) ? wp.y : wp.x) * mkA;
            dsum += wg;
            float2 u;
            u = unpack_bf2(gvA.x); acc[0] = fmaf(wg, u.x, acc[0]); acc[1] = fmaf(wg, u.y, acc[1]);
            u = unpack_bf2(gvA.y); acc[2] = fmaf(wg, u.x, acc[2]); acc[3] = fmaf(wg, u.y, acc[3]);
            u = unpack_bf2(gvA.z); acc[4] = fmaf(wg, u.x, acc[4]); acc[5] = fmaf(wg, u.y, acc[5]);
            u = unpack_bf2(gvA.w); acc[6] = fmaf(wg, u.x, acc[6]); acc[7] = fmaf(wg, u.y, acc[7]);
            meA = meB; gvA = gvB; meB = meC; mkA = mkB; mkB = mn;
        }
        float2 w01 = unpack_bf2(meA.y);
        float2 w23 = unpack_bf2(meA.z);
        float2 wp = (h < 2) ? w01 : w23;
        float wg = ((h & 1) ? wp.y : wp.x) * mkA;
        dsum += wg;
        float2 u;
        u = unpack_bf2(gvA.x); acc[0] = fmaf(wg, u.x, acc[0]); acc[1] = fmaf(wg, u.y, acc[1]);
        u = unpack_bf2(gvA.y); acc[2] = fmaf(wg, u.x, acc[2]); acc[3] = fmaf(wg, u.y, acc[3]);
        u = unpack_bf2(gvA.z); acc[4] = fmaf(wg, u.x, acc[4]); acc[5] = fmaf(wg, u.y, acc[5]);
        u = unpack_bf2(gvA.w); acc[6] = fmaf(wg, u.x, acc[6]); acc[7] = fmaf(wg, u.y, acc[7]);
    }
#pragma unroll
    for (int k = 0; k < 8; ++k) acc[k] += __shfl_xor(acc[k], 32);
    dsum += __shfl_xor(dsum, 32);
    if (g == 0) {
        float inv = 1.f / dsum;
        const float* bp = bias + c32 * 8;
        float4 b0 = *(const float4*)bp;
        float4 b1 = *(const float4*)(bp + 4);
        uint4 o;
        o.x = pack_bf2(fmaf(acc[0], inv, b0.x), fmaf(acc[1], inv, b0.y));
        o.y = pack_bf2(fmaf(acc[2], inv, b0.z), fmaf(acc[3], inv, b0.w));
        o.z = pack_bf2(fmaf(acc[4], inv, b1.x), fmaf(acc[5], inv, b1.y));
        o.w = pack_bf2(fmaf(acc[6], inv, b1.z), fmaf(acc[7], inv, b1.w));
        ((uint4*)out)[(size_t)n * 32 + c32] = o;
    }
}

// ---------------- layer-2 aggregation: 1 wave/node, 4 groups x 16 col-chunks ----------------
__global__ __launch_bounds__(256) void k_agg2(const ushort* __restrict__ h2,
                                              const int* __restrict__ row_ptr,
                                              const float4* __restrict__ wm,
                                              const float* __restrict__ al_s,
                                              const float* __restrict__ al_d,
                                              const float* __restrict__ lE,
                                              const float* __restrict__ bias,
                                              ushort* __restrict__ out, int N) {
    int n = blockIdx.x * 4 + (threadIdx.x >> 6);
    if (n >= N) return;
    int lane = threadIdx.x & 63;
    int g = lane >> 4, c16 = lane & 15;
    bool hi = c16 >= 8;
    const uint4* h2u4 = (const uint4*)h2;
    float2 ad = *(const float2*)(al_d + 2 * (size_t)n);
    float2 as = *(const float2*)(al_s + 2 * (size_t)n);
    float wsA = __expf(lrelu(as.x + ad.x + lE[0]));
    float wsB = __expf(lrelu(as.y + ad.y + lE[1]));
    uint4 hs = h2u4[(size_t)n * 16 + c16];
    float wself = (g == 0) ? (hi ? wsB : wsA) : 0.f;
    float dsum = wself;
    float acc[8];
    {
        float2 t0 = unpack_bf2(hs.x), t1 = unpack_bf2(hs.y);
        float2 t2 = unpack_bf2(hs.z), t3 = unpack_bf2(hs.w);
        acc[0] = wself * t0.x; acc[1] = wself * t0.y;
        acc[2] = wself * t1.x; acc[3] = wself * t1.y;
        acc[4] = wself * t2.x; acc[5] = wself * t2.y;
        acc[6] = wself * t3.x; acc[7] = wself * t3.y;
    }
    int i0 = row_ptr[n];
    int cnt = row_ptr[n + 1] - i0;
    if (cnt > 0) {
        int last = cnt - 1;
        int j0 = g; float m0 = 1.f;
        if (j0 > last) { j0 = last; m0 = 0.f; }
        int j1 = 4 + g; float m1 = 1.f;
        if (j1 > last) { j1 = last; m1 = 0.f; }
        float4 meA = wm[i0 + j0];
        uint4 gvA = h2u4[(size_t)__float_as_int(meA.x) * 16 + c16];
        float4 meB = wm[i0 + j1];
        float mkA = m0, mkB = m1;
        int nit = (cnt + 3) >> 2;
        for (int it = 1; it < nit; ++it) {
            uint4 gvB = h2u4[(size_t)__float_as_int(meB.x) * 16 + c16];
            int jn = 4 * (it + 1) + g;
            float mn = 1.f;
            if (jn > last) { jn = last; mn = 0.f; }
            float4 meC = wm[i0 + jn];
            float wg = (hi ? meA.z : meA.y) * mkA;
            dsum += wg;
            float2 u;
            u = unpack_bf2(gvA.x); acc[0] = fmaf(wg, u.x, acc[0]); acc[1] = fmaf(wg, u.y, acc[1]);
            u = unpack_bf2(gvA.y); acc[2] = fmaf(wg, u.x, acc[2]); acc[3] = fmaf(wg, u.y, acc[3]);
            u = unpack_bf2(gvA.z); acc[4] = fmaf(wg, u.x, acc[4]); acc[5] = fmaf(wg, u.y, acc[5]);
            u = unpack_bf2(gvA.w); acc[6] = fmaf(wg, u.x, acc[6]); acc[7] = fmaf(wg, u.y, acc[7]);
            meA = meB; gvA = gvB; meB = meC; mkA = mkB; mkB = mn;
        }
        float wg = (hi ? meA.z : meA.y) * mkA;
        dsum += wg;
        float2 u;
        u = unpack_bf2(gvA.x); acc[0] = fmaf(wg, u.x, acc[0]); acc[1] = fmaf(wg, u.y, acc[1]);
        u = unpack_bf2(gvA.y); acc[2] = fmaf(wg, u.x, acc[2]); acc[3] = fmaf(wg, u.y, acc[3]);
        u = unpack_bf2(gvA.z); acc[4] = fmaf(wg, u.x, acc[4]); acc[5] = fmaf(wg, u.y, acc[5]);
        u = unpack_bf2(gvA.w); acc[6] = fmaf(wg, u.x, acc[6]); acc[7] = fmaf(wg, u.y, acc[7]);
    }
#pragma unroll
    for (int k = 0; k < 8; ++k) {
        acc[k] += __shfl_xor(acc[k], 16);
        acc[k] += __shfl_xor(acc[k], 32);
    }
    dsum += __shfl_xor(dsum, 16);
    dsum += __shfl_xor(dsum, 32);
    if (g == 0) {
        float inv = 1.f / dsum;
        const float* bp = bias + c16 * 8;
        float4 b0 = *(const float4*)bp;
        float4 b1 = *(const float4*)(bp + 4);
        uint4 o;
        o.x = pack_bf2(fmaf(acc[0], inv, b0.x), fmaf(acc[1], inv, b0.y));
        o.y = pack_bf2(fmaf(acc[2], inv, b0.z), fmaf(acc[3], inv, b0.w));
        o.z = pack_bf2(fmaf(acc[4], inv, b1.x), fmaf(acc[5], inv, b1.y));
        o.w = pack_bf2(fmaf(acc[6], inv, b1.z), fmaf(acc[7], inv, b1.w));
        ((uint4*)out)[(size_t)n * 16 + c16] = o;
    }
}

// ---------------- GraphNorm column stats: uint4 streaming + LDS tree + few atomics ----------
template <int C4>
__global__ __launch_bounds__(256) void k_stats_bf(const ushort* __restrict__ x,
                                                  float* __restrict__ stats, int rows) {
    const int C = C4 * 8;
    const int RG = 256 / C4;
    int t = threadIdx.x;
    int c = t & (C4 - 1);
    int rg = t / C4;
    int rpb = (rows + gridDim.x - 1) / gridDim.x;
    int r0 = blockIdx.x * rpb;
    int r1 = r0 + rpb;
    if (r1 > rows) r1 = rows;
    const uint4* xu = (const uint4*)x;
    float s[8] = {0.f, 0.f, 0.f, 0.f, 0.f, 0.f, 0.f, 0.f};
    float q[8] = {0.f, 0.f, 0.f, 0.f, 0.f, 0.f, 0.f, 0.f};
    for (int r = r0 + rg; r < r1; r += RG) {
        uint4 v = xu[(size_t)r * C4 + c];
        float2 a0 = unpack_bf2(v.x), a1 = unpack_bf2(v.y);
        float2 a2 = unpack_bf2(v.z), a3 = unpack_bf2(v.w);
        s[0] += a0.x; q[0] = fmaf(a0.x, a0.x, q[0]);
        s[1] += a0.y; q[1] = fmaf(a0.y, a0.y, q[1]);
        s[2] += a1.x; q[2] = fmaf(a1.x, a1.x, q[2]);
        s[3] += a1.y; q[3] = fmaf(a1.y, a1.y, q[3]);
        s[4] += a2.x; q[4] = fmaf(a2.x, a2.x, q[4]);
        s[5] += a2.y; q[5] = fmaf(a2.y, a2.y, q[5]);
        s[6] += a3.x; q[6] = fmaf(a3.x, a3.x, q[6]);
        s[7] += a3.y; q[7] = fmaf(a3.y, a3.y, q[7]);
    }
    __shared__ float ls[256 * 16];
#pragma unroll
    for (int k = 0; k < 8; ++k) {
        ls[t * 16 + k] = s[k];
        ls[t * 16 + 8 + k] = q[k];
    }
    __syncthreads();
    if (t < C) {
        int cc = t >> 3, k = t & 7;
        float ssum = 0.f, qsum = 0.f;
#pragma unroll
        for (int g = 0; g < RG; ++g) {
            ssum += ls[(g * C4 + cc) * 16 + k];
            qsum += ls[(g * C4 + cc) * 16 + 8 + k];
        }
        atomicAdd(&stats[t], ssum);
        atomicAdd(&stats[C + t], qsum);
    }
}

__global__ void k_coef(const float* __restrict__ stats, const float* __restrict__ w,
                       const float* __restrict__ b, const float* __restrict__ ms,
                       float* __restrict__ AB, int rows) {
    int C = blockDim.x, col = threadIdx.x;
    float inv = 1.f / (float)rows;
    float mean = stats[col] * inv;
    float c = mean * ms[col];
    float var = stats[C + col] * inv - 2.f * c * mean + c * c;
    float A = w[col] * rsqrtf(var + GEPS);
    AB[col] = A;
    AB[C + col] = b[col] - A * c;
}

// ---------------- MFMA GEMM2 + fused layer-2 attn dots ----------------
__global__ __launch_bounds__(256) void k_gemm2_mfma(const ushort* __restrict__ X,
                                                    const float* __restrict__ AB,
                                                    const uint4* __restrict__ Bfrag,
                                                    const float* __restrict__ as2,
                                                    const float* __restrict__ ad2,
                                                    ushort* __restrict__ H2,
                                                    float* __restrict__ al_s,
                                                    float* __restrict__ al_d, int Nn) {
    int wave = threadIdx.x >> 6, lane = threadIdx.x & 63;
    int q = lane >> 4, m = lane & 15;
    int rowbase = blockIdx.x * 64 + wave * 16;
    int row = rowbase + m;
    bool valid = row < Nn;
    floatx4 acc[8];
#pragma unroll
    for (int c = 0; c < 8; ++c) acc[c] = (floatx4){0.f, 0.f, 0.f, 0.f};
    const uint4* xr4 = (const uint4*)((const unsigned int*)X + (size_t)row * 128);
#pragma unroll
    for (int kk = 0; kk < 8; ++kk) {
        int k0 = kk * 32 + q * 8;
        uint4 xu = valid ? xr4[k0 >> 3] : make_uint4(0, 0, 0, 0);
        float2 x01 = unpack_bf2(xu.x);
        float2 x23 = unpack_bf2(xu.y);
        float2 x45 = unpack_bf2(xu.z);
        float2 x67 = unpack_bf2(xu.w);
        float4 a0 = *(const float4*)(AB + k0);
        float4 a1 = *(const float4*)(AB + k0 + 4);
        float4 b0 = *(const float4*)(AB + 256 + k0);
        float4 b1 = *(const float4*)(AB + 256 + k0 + 4);
        float v0 = fmaf(a0.x, x01.x, b0.x);
        float v1 = fmaf(a0.y, x01.y, b0.y);
        float v2 = fmaf(a0.z, x23.x, b0.z);
        float v3 = fmaf(a0.w, x23.y, b0.w);
        float v4 = fmaf(a1.x, x45.x, b1.x);
        float v5 = fmaf(a1.y, x45.y, b1.y);
        float v6 = fmaf(a1.z, x67.x, b1.z);
        float v7 = fmaf(a1.w, x67.y, b1.w);
        v0 = (v0 > 0.f) ? v0 : expm1f(v0);
        v1 = (v1 > 0.f) ? v1 : expm1f(v1);
        v2 = (v2 > 0.f) ? v2 : expm1f(v2);
        v3 = (v3 > 0.f) ? v3 : expm1f(v3);
        v4 = (v4 > 0.f) ? v4 : expm1f(v4);
        v5 = (v5 > 0.f) ? v5 : expm1f(v5);
        v6 = (v6 > 0.f) ? v6 : expm1f(v6);
        v7 = (v7 > 0.f) ? v7 : expm1f(v7);
        union { short8 s; unsigned int u[4]; } af;
        af.u[0] = pack_bf2(v0, v1);
        af.u[1] = pack_bf2(v2, v3);
        af.u[2] = pack_bf2(v4, v5);
        af.u[3] = pack_bf2(v6, v7);
        const uint4* bp = Bfrag + kk * 64 + lane;
#pragma unroll
        for (int c = 0; c < 8; ++c) {
            union { short8 s; uint4 u; } bf;
            bf.u = bp[c * 8 * 64];
            acc[c] = __builtin_amdgcn_mfma_f32_16x16x32_bf16(af.s, bf.s, acc[c], 0, 0, 0);
        }
    }
    float a_s[8], a_d[8];
#pragma unroll
    for (int c = 0; c < 8; ++c) {
        a_s[c] = as2[c * 16 + m];
        a_d[c] = ad2[c * 16 + m];
    }
#pragma unroll
    for (int r = 0; r < 4; ++r) {
        int orow = rowbase + q * 4 + r;
        bool vr = orow < Nn;
        ushort us[8];
        float s0 = 0.f, s1 = 0.f, d0 = 0.f, d1 = 0.f;
#pragma unroll
        for (int c = 0; c < 8; ++c) {
            us[c] = f2bf(acc[c][r]);
            float v = bf2f(us[c]);
            if (c < 4) {
                s0 = fmaf(v, a_s[c], s0);
                d0 = fmaf(v, a_d[c], d0);
            } else {
                s1 = fmaf(v, a_s[c], s1);
                d1 = fmaf(v, a_d[c], d1);
            }
        }
#pragma unroll
        for (int o = 1; o < 16; o <<= 1) {
            s0 += __shfl_xor(s0, o);
            s1 += __shfl_xor(s1, o);
            d0 += __shfl_xor(d0, o);
            d1 += __shfl_xor(d1, o);
        }
        if (vr) {
            ushort* op = H2 + (size_t)orow * 128 + m;
#pragma unroll
            for (int c = 0; c < 8; ++c) op[c * 16] = us[c];
            if (m == 0) {
                *(float2*)(al_s + 2 * (size_t)orow) = make_float2(s0, s1);
                *(float2*)(al_d + 2 * (size_t)orow) = make_float2(d0, d1);
            }
        }
    }
}

// ---------------- classifier with fused GraphNorm+ELU, bf16 input ----------------
__global__ __launch_bounds__(256) void k_cls(const ushort* __restrict__ X,
                                             const float* __restrict__ AB,
                                             const float* __restrict__ Wc,
                                             const float* __restrict__ bc,
                                             float* __restrict__ out, int Nn) {
    __shared__ __align__(16) float ls[16 * 132];
    __shared__ __align__(16) float wT[13 * 132];
    __shared__ float bS[13];
    int t = threadIdx.x;
    int n0 = blockIdx.x * 16;
    for (int i = t; i < 128 * 13; i += 256) {
        int k = i / 13, j = i - k * 13;
        wT[j * 132 + k] = Wc[i];
    }
    if (t < 13) bS[t] = bc[t];
    const unsigned int* xu = (const unsigned int*)X;
    for (int idx = t; idx < 16 * 64; idx += 256) {
        int r = idx >> 6, ku = idx & 63;
        int row = n0 + r;
        float vx = 0.f, vy = 0.f;
        if (row < Nn) {
            float2 v = unpack_bf2(xu[(size_t)row * 64 + ku]);
            int k = 2 * ku;
            vx = fmaf(AB[k], v.x, AB[128 + k]);
            vy = fmaf(AB[k + 1], v.y, AB[128 + k + 1]);
            vx = (vx > 0.f) ? vx : expm1f(vx);
            vy = (vy > 0.f) ? vy : expm1f(vy);
        }
        ls[r * 132 + 2 * ku] = vx;
        ls[r * 132 + 2 * ku + 1] = vy;
    }
    __syncthreads();
    if (t < 208) {
        int r = t / 13, j = t - r * 13;
        int row = n0 + r;
        if (row < Nn) {
            float acc = bS[j];
            const float* lr = &ls[r * 132];
            const float* wr = &wT[j * 132];
#pragma unroll 8
            for (int k = 0; k < 128; k += 4) {
                float4 a = *(const float4*)&lr[k];
                float4 b = *(const float4*)&wr[k];
                acc = fmaf(a.x, b.x, fmaf(a.y, b.y, fmaf(a.z, b.z, fmaf(a.w, b.w, acc))));
            }
            out[(size_t)row * 13 + j] = acc;
        }
    }
}

extern "C" void kernel_launch(void* const* d_in, const int* in_sizes, int n_in, void* d_out,
                              int out_size, void* d_ws, size_t ws_size, hipStream_t stream) {
    const float* x = (const float*)d_in[0];
    const int* edge_index = (const int*)d_in[1];
    const float* edge_attr = (const float*)d_in[2];
    const float* W1 = (const float*)d_in[3];
    const float* We1 = (const float*)d_in[4];
    const float* as1 = (const float*)d_in[5];
    const float* ad1 = (const float*)d_in[6];
    const float* ae1 = (const float*)d_in[7];
    const float* b1 = (const float*)d_in[8];
    const float* gn1_w = (const float*)d_in[9];
    const float* gn1_b = (const float*)d_in[10];
    const float* gn1_ms = (const float*)d_in[11];
    const float* W2 = (const float*)d_in[12];
    const float* We2 = (const float*)d_in[13];
    const float* as2 = (const float*)d_in[14];
    const float* ad2 = (const float*)d_in[15];
    const float* ae2 = (const float*)d_in[16];
    const float* b2 = (const float*)d_in[17];
    const float* gn2_w = (const float*)d_in[18];
    const float* gn2_b = (const float*)d_in[19];
    const float* gn2_ms = (const float*)d_in[20];
    const float* Wc = (const float*)d_in[21];
    const float* bc = (const float*)d_in[22];

    const int N = in_sizes[0] / 3;
    const int E = in_sizes[1] / 2;
    const int* srcv = edge_index;
    const int* dstv = edge_index + E;

    // ---- workspace carve (256B-aligned, byte-based) ----
    char* w = (char*)d_ws;
    auto carveB = [&](size_t bytes) -> void* {
        void* p = (void*)w;
        w += ((bytes + 255) / 256) * 256;
        return p;
    };
    // zeroed region first:
    int* deg = (int*)carveB((size_t)N * 4);
    int* cursor = (int*)carveB((size_t)N * 4);
    float* ea_sum = (float*)carveB(8);
    float* statsA = (float*)carveB(512 * 4);
    float* statsB = (float*)carveB(256 * 4);
    char* zero_end = w;
    // not zeroed:
    int* row_ptr = (int*)carveB((size_t)(N + 1) * 4);
    int* bsum = (int*)carveB(1024 * 4);
    int* si = (int*)carveB((size_t)E * 4);
    int* dstc = (int*)carveB((size_t)E * 4);
    float2* eacsr = (float2*)carveB((size_t)E * 8);
    uint4* wmp = (uint4*)carveB((size_t)E * 16);
    float4* wm2 = (float4*)wmp;  // layer-2 weights reuse (wmp dead after agg1)
    float* C1 = (float*)carveB(8 * 4);
    float* lE1 = (float*)carveB(4 * 4);
    float* C2 = (float*)carveB(4 * 4);
    float* lE2 = (float*)carveB(2 * 4);
    float* AB1 = (float*)carveB(512 * 4);
    float* AB2 = (float*)carveB(256 * 4);
    uint4* Bfrag = (uint4*)carveB(4096 * 16);
    float* al_s1 = (float*)carveB((size_t)N * 4 * 4);
    float* al_d1 = (float*)carveB((size_t)N * 4 * 4);
    float* al_s2 = (float*)carveB((size_t)N * 2 * 4);
    float* al_d2 = (float*)carveB((size_t)N * 2 * 4);
    ushort* h1b = (ushort*)carveB((size_t)N * 256 * 2);   // bf16 h1; later aliased by out2b
    ushort* h2b = (ushort*)carveB((size_t)N * 128 * 2);   // bf16 h2
    ushort* out1b = (ushort*)carveB((size_t)N * 256 * 2); // bf16 layer-1 output
    ushort* out2b = h1b;                                  // bf16 layer-2 output (h1b dead)

    hipMemsetAsync(deg, 0, (size_t)(zero_end - (char*)deg), stream);

    const int nb1 = (N + 1023) / 1024;
    const int ebl = (E + 255) / 256;

    k_ea_deg<<<256, 256, 0, stream>>>(edge_attr, dstv, ea_sum, deg, E);
    k_scan1<<<nb1, 1024, 0, stream>>>(deg, row_ptr, bsum, N);
    k_scan23<<<nb1, 1024, 0, stream>>>(row_ptr, bsum, N);
    k_w2frag<<<17, 256, 0, stream>>>(W2, Bfrag, We1, ae1, We2, ae2, ea_sum, E, C1, lE1, C2, lE2);

    // ---- layer 1 ----
    k_l1<<<(N + 1) / 2, 256, 0, stream>>>(x, W1, as1, ad1, h1b, al_s1, al_d1, N);
    k_scatfill<<<ebl, 256, 0, stream>>>(dstv, srcv, edge_attr, row_ptr, cursor, al_s1, al_d1, C1,
                                        si, dstc, eacsr, wmp, E);
    k_agg1<<<(N + 3) / 4, 256, 0, stream>>>(h1b, row_ptr, wmp, al_s1, al_d1, lE1, b1, out1b, N);
    k_stats_bf<32><<<256, 256, 0, stream>>>(out1b, statsA, N);
    k_coef<<<1, 256, 0, stream>>>(statsA, gn1_w, gn1_b, gn1_ms, AB1, N);

    // ---- layer 2 (norm+ELU fused into MFMA GEMM A-load; attn dots fused in epilogue) ----
    k_gemm2_mfma<<<(N + 63) / 64, 256, 0, stream>>>(out1b, AB1, Bfrag, as2, ad2, h2b, al_s2,
                                                    al_d2, N);
    k_fill2<<<ebl, 256, 0, stream>>>(si, dstc, eacsr, al_s2, al_d2, C2, wm2, E);
    k_agg2<<<(N + 3) / 4, 256, 0, stream>>>(h2b, row_ptr, wm2, al_s2, al_d2, lE2, b2, out2b, N);
    k_stats_bf<16><<<256, 256, 0, stream>>>(out2b, statsB, N);
    k_coef<<<1, 128, 0, stream>>>(statsB, gn2_w, gn2_b, gn2_ms, AB2, N);

    // ---- classifier (norm+ELU fused) ----
    k_cls<<<(N + 15) / 16, 256, 0, stream>>>(out2b, AB2, Wc, bc, (float*)d_out, N);
}

// Round 13
// 337.695 us; speedup vs baseline: 1.0738x; 1.0199x over previous
//
#include <hip/hip_runtime.h>
#include <math.h>

#define NEG_SLOPE 0.2f
#define GEPS 1e-5f

typedef __attribute__((ext_vector_type(8))) short short8;
typedef __attribute__((ext_vector_type(4))) float floatx4;

__device__ __forceinline__ float wave_reduce_sum(float v) {
#pragma unroll
    for (int o = 32; o > 0; o >>= 1) v += __shfl_down(v, o);
    return v;
}

__device__ __forceinline__ ushort f2bf(float f) {
    union { float f; unsigned int i; } c;
    c.f = f;
    unsigned int b = c.i;
    b += 0x7fffu + ((b >> 16) & 1u);
    return (ushort)(b >> 16);
}

__device__ __forceinline__ float bf2f(ushort u) {
    union { unsigned int i; float f; } c;
    c.i = (unsigned int)u << 16;
    return c.f;
}

__device__ __forceinline__ float2 unpack_bf2(unsigned int u) {
    union { unsigned int i; float f; } a, b;
    a.i = u << 16;            // low ushort -> even col
    b.i = u & 0xffff0000u;    // high ushort -> odd col
    return make_float2(a.f, b.f);
}

__device__ __forceinline__ unsigned int pack_bf2(float lo, float hi) {
    return (unsigned int)f2bf(lo) | ((unsigned int)f2bf(hi) << 16);
}

__device__ __forceinline__ float lrelu(float v) {
    return (v > 0.f) ? v : v * NEG_SLOPE;
}

__device__ __forceinline__ float elu_fast(float v) {
    return (v > 0.f) ? v : (__expf(v) - 1.f);
}

// ---------------- edge_attr column sums + degree count (merged) ----------------
__global__ void k_ea_deg(const float* __restrict__ ea, const int* __restrict__ dst,
                         float* __restrict__ ea_sum, int* __restrict__ deg, int E) {
    const float2* ea2 = (const float2*)ea;
    float s0 = 0.f, s1 = 0.f;
    int stride = gridDim.x * blockDim.x;
    for (int e = blockIdx.x * blockDim.x + threadIdx.x; e < E; e += stride) {
        float2 v = ea2[e];
        s0 += v.x; s1 += v.y;
        atomicAdd(&deg[dst[e]], 1);
    }
    s0 = wave_reduce_sum(s0);
    s1 = wave_reduce_sum(s1);
    if ((threadIdx.x & 63) == 0) {
        atomicAdd(&ea_sum[0], s0);
        atomicAdd(&ea_sum[1], s1);
    }
}

// ---------------- CSR row_ptr scan (block-local) ----------------
__global__ void k_scan1(const int* __restrict__ deg, int* __restrict__ row_ptr,
                        int* __restrict__ bsum, int N) {
    __shared__ int tmp[1024];
    int tid = threadIdx.x;
    int i = blockIdx.x * 1024 + tid;
    int v = (i < N) ? deg[i] : 0;
    tmp[tid] = v;
    __syncthreads();
#pragma unroll
    for (int off = 1; off < 1024; off <<= 1) {
        int t = (tid >= off) ? tmp[tid - off] : 0;
        __syncthreads();
        tmp[tid] += t;
        __syncthreads();
    }
    if (i < N) row_ptr[i + 1] = tmp[tid];
    if (tid == 1023) bsum[blockIdx.x] = tmp[1023];
}

// block prefix recomputed per block in one wave (nb1 <= 64), then applied
__global__ void k_scan23(int* __restrict__ row_ptr, const int* __restrict__ bsum, int N) {
    __shared__ int off_s;
    int t = threadIdx.x;
    if (t < 64) {
        int v = (t < blockIdx.x) ? bsum[t] : 0;
#pragma unroll
        for (int o = 32; o > 0; o >>= 1) v += __shfl_xor(v, o);
        if (t == 0) off_s = v;
    }
    __syncthreads();
    int off = off_s;
    int i = blockIdx.x * 1024 + t;
    if (i == 0) row_ptr[0] = 0;
    if (i < N) row_ptr[i + 1] += off;
}

// ---------------- W2 -> bf16 MFMA B-fragment layout, + attn consts (block 16) ----------------
__global__ void k_w2frag(const float* __restrict__ W2, uint4* __restrict__ Bfrag,
                         const float* __restrict__ We1, const float* __restrict__ ae1,
                         const float* __restrict__ We2, const float* __restrict__ ae2,
                         const float* __restrict__ ea_sum, int E,
                         float* __restrict__ C1, float* __restrict__ lE1,
                         float* __restrict__ C2, float* __restrict__ lE2) {
    if (blockIdx.x == 16) {
        int t = threadIdx.x, h = t >> 6, lane = t & 63;
        float p0 = We1[t] * ae1[t];
        float p1 = We1[256 + t] * ae1[t];
        p0 = wave_reduce_sum(p0);
        p1 = wave_reduce_sum(p1);
        if (lane == 0) { C1[h] = p0; C1[4 + h] = p1; }
        if (t < 128) {
            float q0 = We2[t] * ae2[t];
            float q1 = We2[128 + t] * ae2[t];
            q0 = wave_reduce_sum(q0);
            q1 = wave_reduce_sum(q1);
            if (lane == 0) { C2[h] = q0; C2[2 + h] = q1; }
        }
        __syncthreads();
        float m0 = ea_sum[0] / (float)E, m1 = ea_sum[1] / (float)E;
        if (t < 4) lE1[t] = m0 * C1[t] + m1 * C1[4 + t];
        if (t < 2) lE2[t] = m0 * C2[t] + m1 * C2[2 + t];
        return;
    }
    int t = blockIdx.x * 256 + threadIdx.x;  // 4096 threads
    int c = t >> 9, kk = (t >> 6) & 7, L = t & 63;
    int q = L >> 4, n = c * 16 + (L & 15);
    int k0 = kk * 32 + q * 8;
    unsigned int u0 = pack_bf2(W2[(k0 + 0) * 128 + n], W2[(k0 + 1) * 128 + n]);
    unsigned int u1 = pack_bf2(W2[(k0 + 2) * 128 + n], W2[(k0 + 3) * 128 + n]);
    unsigned int u2 = pack_bf2(W2[(k0 + 4) * 128 + n], W2[(k0 + 5) * 128 + n]);
    unsigned int u3 = pack_bf2(W2[(k0 + 6) * 128 + n], W2[(k0 + 7) * 128 + n]);
    Bfrag[t] = make_uint4(u0, u1, u2, u3);
}

// ---------------- layer-1 transform: 2 nodes per 256-thread block ----------------
__global__ __launch_bounds__(256) void k_l1(const float* __restrict__ x,
                                            const float* __restrict__ W1,
                                            const float* __restrict__ as1,
                                            const float* __restrict__ ad1,
                                            ushort* __restrict__ h1, float* __restrict__ al_s,
                                            float* __restrict__ al_d, int N) {
    int u = threadIdx.x >> 7;
    int n = blockIdx.x * 2 + u;
    if (n >= N) return;
    int t = threadIdx.x & 127, lane = threadIdx.x & 63;
    int c0 = 2 * t;
    float x0 = x[3 * n], x1 = x[3 * n + 1], x2 = x[3 * n + 2];
    float h0 = fmaf(x0, W1[c0], fmaf(x1, W1[256 + c0], x2 * W1[512 + c0]));
    float h1v = fmaf(x0, W1[c0 + 1], fmaf(x1, W1[257 + c0], x2 * W1[513 + c0]));
    ((unsigned int*)h1)[(size_t)n * 128 + t] = pack_bf2(h0, h1v);
    float ps = h0 * as1[c0] + h1v * as1[c0 + 1];
    float pd = h0 * ad1[c0] + h1v * ad1[c0 + 1];
#pragma unroll
    for (int o = 16; o > 0; o >>= 1) {
        ps += __shfl_xor(ps, o);
        pd += __shfl_xor(pd, o);
    }
    if ((lane & 31) == 0) {
        int h = c0 >> 6;
        al_s[n * 4 + h] = ps;
        al_d[n * 4 + h] = pd;
    }
}

// ---------------- CSR scatter fused with layer-1 edge-weight computation ----------------
__global__ void k_scatfill(const int* __restrict__ dst, const int* __restrict__ src,
                           const float* __restrict__ ea, const int* __restrict__ row_ptr,
                           int* __restrict__ cursor, const float* __restrict__ al_s1,
                           const float* __restrict__ al_d1, const float* __restrict__ C1,
                           int* __restrict__ si, int* __restrict__ dstc,
                           float2* __restrict__ eacsr, uint4* __restrict__ wmp, int E) {
    int e = blockIdx.x * 256 + threadIdx.x;
    if (e >= E) return;
    int d = dst[e];
    int pos = atomicAdd(&cursor[d], 1);
    int slot = row_ptr[d] + pos;
    int s = src[e];
    float2 v = ((const float2*)ea)[e];
    float4 as = *(const float4*)(al_s1 + 4 * (size_t)s);
    float4 ad = *(const float4*)(al_d1 + 4 * (size_t)d);
    float w0 = __expf(lrelu(as.x + ad.x + v.x * C1[0] + v.y * C1[4]));
    float w1 = __expf(lrelu(as.y + ad.y + v.x * C1[1] + v.y * C1[5]));
    float w2 = __expf(lrelu(as.z + ad.z + v.x * C1[2] + v.y * C1[6]));
    float w3 = __expf(lrelu(as.w + ad.w + v.x * C1[3] + v.y * C1[7]));
    si[slot] = s;
    dstc[slot] = d;
    eacsr[slot] = v;
    wmp[slot] = make_uint4((unsigned int)s, pack_bf2(w0, w1), pack_bf2(w2, w3), 0u);
}

// ---------------- layer-2 edge-weight fill (CSR order) ----------------
__global__ void k_fill2(const int* __restrict__ si, const int* __restrict__ dstc,
                        const float2* __restrict__ eacsr, const float* __restrict__ al_s2,
                        const float* __restrict__ al_d2, const float* __restrict__ C2,
                        float4* __restrict__ wm2, int E) {
    int e = blockIdx.x * 256 + threadIdx.x;
    if (e >= E) return;
    int s = si[e], d = dstc[e];
    float2 v = eacsr[e];
    float2 as = *(const float2*)(al_s2 + 2 * (size_t)s);
    float2 ad = *(const float2*)(al_d2 + 2 * (size_t)d);
    float wA = __expf(lrelu(as.x + ad.x + v.x * C2[0] + v.y * C2[2]));
    float wB = __expf(lrelu(as.y + ad.y + v.x * C2[1] + v.y * C2[3]));
    wm2[e] = make_float4(__int_as_float(s), wA, wB, 0.f);
}

// ---------------- layer-1 aggregation: one wave per node, full 512B row ----------------
__global__ __launch_bounds__(256) void k_agg1(const ushort* __restrict__ h1,
                                              const int* __restrict__ row_ptr,
                                              const uint4* __restrict__ wmp,
                                              const float* __restrict__ al_s,
                                              const float* __restrict__ al_d,
                                              const float* __restrict__ lE,
                                              const float* __restrict__ bias,
                                              ushort* __restrict__ out, int N) {
    int n = blockIdx.x * 4 + (threadIdx.x >> 6);
    if (n >= N) return;
    int lane = threadIdx.x & 63;
    int g = lane >> 5, c32 = lane & 31;
    int h = c32 >> 3;
    const uint4* h1u4 = (const uint4*)h1;
    float4 as = *(const float4*)(al_s + 4 * (size_t)n);
    float4 ad = *(const float4*)(al_d + 4 * (size_t)n);
    float4 le = *(const float4*)lE;
    float ws0 = __expf(lrelu(as.x + ad.x + le.x));
    float ws1 = __expf(lrelu(as.y + ad.y + le.y));
    float ws2 = __expf(lrelu(as.z + ad.z + le.z));
    float ws3 = __expf(lrelu(as.w + ad.w + le.w));
    float wsh = (h == 0) ? ws0 : (h == 1) ? ws1 : (h == 2) ? ws2 : ws3;
    uint4 hs = h1u4[(size_t)n * 32 + c32];
    float wself = (g == 0) ? wsh : 0.f;
    float dsum = wself;
    float acc[8];
    {
        float2 t0 = unpack_bf2(hs.x), t1 = unpack_bf2(hs.y);
        float2 t2 = unpack_bf2(hs.z), t3 = unpack_bf2(hs.w);
        acc[0] = wself * t0.x; acc[1] = wself * t0.y;
        acc[2] = wself * t1.x; acc[3] = wself * t1.y;
        acc[4] = wself * t2.x; acc[5] = wself * t2.y;
        acc[6] = wself * t3.x; acc[7] = wself * t3.y;
    }
    int i0 = row_ptr[n];
    int cnt = row_ptr[n + 1] - i0;
    if (cnt > 0) {
        int last = cnt - 1;
        int j0 = g; float m0 = 1.f;
        if (j0 > last) { j0 = last; m0 = 0.f; }
        int j1 = 2 + g; float m1 = 1.f;
        if (j1 > last) { j1 = last; m1 = 0.f; }
        uint4 meA = wmp[i0 + j0];
        uint4 gvA = h1u4[(size_t)meA.x * 32 + c32];
        uint4 meB = wmp[i0 + j1];
        float mkA = m0, mkB = m1;
        int nit = (cnt + 1) >> 1;
        for (int it = 1; it < nit; ++it) {
            uint4 gvB = h1u4[(size_t)meB.x * 32 + c32];
            int jn = 2 * (it + 1) + g;
            float mn = 1.f;
            if (jn > last) { jn = last; mn = 0.f; }
            uint4 meC = wmp[i0 + jn];
            float2 w01 = unpack_bf2(meA.y);
            float2 w23 = unpack_bf2(meA.z);
            float2 wp = (h < 2) ? w01 : w23;
            float wg = ((h & 1) ? wp.y : wp.x) * mkA;
            dsum += wg;
            float2 u;
            u = unpack_bf2(gvA.x); acc[0] = fmaf(wg, u.x, acc[0]); acc[1] = fmaf(wg, u.y, acc[1]);
            u = unpack_bf2(gvA.y); acc[2] = fmaf(wg, u.x, acc[2]); acc[3] = fmaf(wg, u.y, acc[3]);
            u = unpack_bf2(gvA.z); acc[4] = fmaf(wg, u.x, acc[4]); acc[5] = fmaf(wg, u.y, acc[5]);
            u = unpack_bf2(gvA.w); acc[6] = fmaf(wg, u.x, acc[6]); acc[7] = fmaf(wg, u.y, acc[7]);
            meA = meB; gvA = gvB; meB = meC; mkA = mkB; mkB = mn;
        }
        float2 w01 = unpack_bf2(meA.y);
        float2 w23 = unpack_bf2(meA.z);
        float2 wp = (h < 2) ? w01 : w23;
        float wg = ((h & 1) ? wp.y : wp.x) * mkA;
        dsum += wg;
        float2 u;
        u = unpack_bf2(gvA.x); acc[0] = fmaf(wg, u.x, acc[0]); acc[1] = fmaf(wg, u.y, acc[1]);
        u = unpack_bf2(gvA.y); acc[2] = fmaf(wg, u.x, acc[2]); acc[3] = fmaf(wg, u.y, acc[3]);
        u = unpack_bf2(gvA.z); acc[4] = fmaf(wg, u.x, acc[4]); acc[5] = fmaf(wg, u.y, acc[5]);
        u = unpack_bf2(gvA.w); acc[6] = fmaf(wg, u.x, acc[6]); acc[7] = fmaf(wg, u.y, acc[7]);
    }
#pragma unroll
    for (int k = 0; k < 8; ++k) acc[k] += __shfl_xor(acc[k], 32);
    dsum += __shfl_xor(dsum, 32);
    if (g == 0) {
        float inv = 1.f / dsum;
        const float* bp = bias + c32 * 8;
        float4 b0 = *(const float4*)bp;
        float4 b1 = *(const float4*)(bp + 4);
        uint4 o;
        o.x = pack_bf2(fmaf(acc[0], inv, b0.x), fmaf(acc[1], inv, b0.y));
        o.y = pack_bf2(fmaf(acc[2], inv, b0.z), fmaf(acc[3], inv, b0.w));
        o.z = pack_bf2(fmaf(acc[4], inv, b1.x), fmaf(acc[5], inv, b1.y));
        o.w = pack_bf2(fmaf(acc[6], inv, b1.z), fmaf(acc[7], inv, b1.w));
        ((uint4*)out)[(size_t)n * 32 + c32] = o;
    }
}

// ---------------- layer-2 aggregation: 1 wave/node, 4 groups x 16 col-chunks ----------------
__global__ __launch_bounds__(256) void k_agg2(const ushort* __restrict__ h2,
                                              const int* __restrict__ row_ptr,
                                              const float4* __restrict__ wm,
                                              const float* __restrict__ al_s,
                                              const float* __restrict__ al_d,
                                              const float* __restrict__ lE,
                                              const float* __restrict__ bias,
                                              ushort* __restrict__ out, int N) {
    int n = blockIdx.x * 4 + (threadIdx.x >> 6);
    if (n >= N) return;
    int lane = threadIdx.x & 63;
    int g = lane >> 4, c16 = lane & 15;
    bool hi = c16 >= 8;
    const uint4* h2u4 = (const uint4*)h2;
    float2 ad = *(const float2*)(al_d + 2 * (size_t)n);
    float2 as = *(const float2*)(al_s + 2 * (size_t)n);
    float wsA = __expf(lrelu(as.x + ad.x + lE[0]));
    float wsB = __expf(lrelu(as.y + ad.y + lE[1]));
    uint4 hs = h2u4[(size_t)n * 16 + c16];
    float wself = (g == 0) ? (hi ? wsB : wsA) : 0.f;
    float dsum = wself;
    float acc[8];
    {
        float2 t0 = unpack_bf2(hs.x), t1 = unpack_bf2(hs.y);
        float2 t2 = unpack_bf2(hs.z), t3 = unpack_bf2(hs.w);
        acc[0] = wself * t0.x; acc[1] = wself * t0.y;
        acc[2] = wself * t1.x; acc[3] = wself * t1.y;
        acc[4] = wself * t2.x; acc[5] = wself * t2.y;
        acc[6] = wself * t3.x; acc[7] = wself * t3.y;
    }
    int i0 = row_ptr[n];
    int cnt = row_ptr[n + 1] - i0;
    if (cnt > 0) {
        int last = cnt - 1;
        int j0 = g; float m0 = 1.f;
        if (j0 > last) { j0 = last; m0 = 0.f; }
        int j1 = 4 + g; float m1 = 1.f;
        if (j1 > last) { j1 = last; m1 = 0.f; }
        float4 meA = wm[i0 + j0];
        uint4 gvA = h2u4[(size_t)__float_as_int(meA.x) * 16 + c16];
        float4 meB = wm[i0 + j1];
        float mkA = m0, mkB = m1;
        int nit = (cnt + 3) >> 2;
        for (int it = 1; it < nit; ++it) {
            uint4 gvB = h2u4[(size_t)__float_as_int(meB.x) * 16 + c16];
            int jn = 4 * (it + 1) + g;
            float mn = 1.f;
            if (jn > last) { jn = last; mn = 0.f; }
            float4 meC = wm[i0 + jn];
            float wg = (hi ? meA.z : meA.y) * mkA;
            dsum += wg;
            float2 u;
            u = unpack_bf2(gvA.x); acc[0] = fmaf(wg, u.x, acc[0]); acc[1] = fmaf(wg, u.y, acc[1]);
            u = unpack_bf2(gvA.y); acc[2] = fmaf(wg, u.x, acc[2]); acc[3] = fmaf(wg, u.y, acc[3]);
            u = unpack_bf2(gvA.z); acc[4] = fmaf(wg, u.x, acc[4]); acc[5] = fmaf(wg, u.y, acc[5]);
            u = unpack_bf2(gvA.w); acc[6] = fmaf(wg, u.x, acc[6]); acc[7] = fmaf(wg, u.y, acc[7]);
            meA = meB; gvA = gvB; meB = meC; mkA = mkB; mkB = mn;
        }
        float wg = (hi ? meA.z : meA.y) * mkA;
        dsum += wg;
        float2 u;
        u = unpack_bf2(gvA.x); acc[0] = fmaf(wg, u.x, acc[0]); acc[1] = fmaf(wg, u.y, acc[1]);
        u = unpack_bf2(gvA.y); acc[2] = fmaf(wg, u.x, acc[2]); acc[3] = fmaf(wg, u.y, acc[3]);
        u = unpack_bf2(gvA.z); acc[4] = fmaf(wg, u.x, acc[4]); acc[5] = fmaf(wg, u.y, acc[5]);
        u = unpack_bf2(gvA.w); acc[6] = fmaf(wg, u.x, acc[6]); acc[7] = fmaf(wg, u.y, acc[7]);
    }
#pragma unroll
    for (int k = 0; k < 8; ++k) {
        acc[k] += __shfl_xor(acc[k], 16);
        acc[k] += __shfl_xor(acc[k], 32);
    }
    dsum += __shfl_xor(dsum, 16);
    dsum += __shfl_xor(dsum, 32);
    if (g == 0) {
        float inv = 1.f / dsum;
        const float* bp = bias + c16 * 8;
        float4 b0 = *(const float4*)bp;
        float4 b1 = *(const float4*)(bp + 4);
        uint4 o;
        o.x = pack_bf2(fmaf(acc[0], inv, b0.x), fmaf(acc[1], inv, b0.y));
        o.y = pack_bf2(fmaf(acc[2], inv, b0.z), fmaf(acc[3], inv, b0.w));
        o.z = pack_bf2(fmaf(acc[4], inv, b1.x), fmaf(acc[5], inv, b1.y));
        o.w = pack_bf2(fmaf(acc[6], inv, b1.z), fmaf(acc[7], inv, b1.w));
        ((uint4*)out)[(size_t)n * 16 + c16] = o;
    }
}

// ---------------- GraphNorm column stats: uint4 streaming + LDS tree + few atomics ----------
template <int C4>
__global__ __launch_bounds__(256) void k_stats_bf(const ushort* __restrict__ x,
                                                  float* __restrict__ stats, int rows) {
    const int C = C4 * 8;
    const int RG = 256 / C4;
    int t = threadIdx.x;
    int c = t & (C4 - 1);
    int rg = t / C4;
    int rpb = (rows + gridDim.x - 1) / gridDim.x;
    int r0 = blockIdx.x * rpb;
    int r1 = r0 + rpb;
    if (r1 > rows) r1 = rows;
    const uint4* xu = (const uint4*)x;
    float s[8] = {0.f, 0.f, 0.f, 0.f, 0.f, 0.f, 0.f, 0.f};
    float q[8] = {0.f, 0.f, 0.f, 0.f, 0.f, 0.f, 0.f, 0.f};
    for (int r = r0 + rg; r < r1; r += RG) {
        uint4 v = xu[(size_t)r * C4 + c];
        float2 a0 = unpack_bf2(v.x), a1 = unpack_bf2(v.y);
        float2 a2 = unpack_bf2(v.z), a3 = unpack_bf2(v.w);
        s[0] += a0.x; q[0] = fmaf(a0.x, a0.x, q[0]);
        s[1] += a0.y; q[1] = fmaf(a0.y, a0.y, q[1]);
        s[2] += a1.x; q[2] = fmaf(a1.x, a1.x, q[2]);
        s[3] += a1.y; q[3] = fmaf(a1.y, a1.y, q[3]);
        s[4] += a2.x; q[4] = fmaf(a2.x, a2.x, q[4]);
        s[5] += a2.y; q[5] = fmaf(a2.y, a2.y, q[5]);
        s[6] += a3.x; q[6] = fmaf(a3.x, a3.x, q[6]);
        s[7] += a3.y; q[7] = fmaf(a3.y, a3.y, q[7]);
    }
    __shared__ float ls[256 * 16];
#pragma unroll
    for (int k = 0; k < 8; ++k) {
        ls[t * 16 + k] = s[k];
        ls[t * 16 + 8 + k] = q[k];
    }
    __syncthreads();
    if (t < C) {
        int cc = t >> 3, k = t & 7;
        float ssum = 0.f, qsum = 0.f;
#pragma unroll
        for (int g = 0; g < RG; ++g) {
            ssum += ls[(g * C4 + cc) * 16 + k];
            qsum += ls[(g * C4 + cc) * 16 + 8 + k];
        }
        atomicAdd(&stats[t], ssum);
        atomicAdd(&stats[C + t], qsum);
    }
}

__global__ void k_coef(const float* __restrict__ stats, const float* __restrict__ w,
                       const float* __restrict__ b, const float* __restrict__ ms,
                       float* __restrict__ AB, int rows) {
    int C = blockDim.x, col = threadIdx.x;
    float inv = 1.f / (float)rows;
    float mean = stats[col] * inv;
    float c = mean * ms[col];
    float var = stats[C + col] * inv - 2.f * c * mean + c * c;
    float A = w[col] * rsqrtf(var + GEPS);
    AB[col] = A;
    AB[C + col] = b[col] - A * c;
}

// ---------------- MFMA GEMM2 + fused layer-2 attn dots (hoisted A-loads, fast ELU) ----------
__global__ __launch_bounds__(256) void k_gemm2_mfma(const ushort* __restrict__ X,
                                                    const float* __restrict__ AB,
                                                    const uint4* __restrict__ Bfrag,
                                                    const float* __restrict__ as2,
                                                    const float* __restrict__ ad2,
                                                    ushort* __restrict__ H2,
                                                    float* __restrict__ al_s,
                                                    float* __restrict__ al_d, int Nn) {
    int wave = threadIdx.x >> 6, lane = threadIdx.x & 63;
    int q = lane >> 4, m = lane & 15;
    int rowbase = blockIdx.x * 64 + wave * 16;
    int row = rowbase + m;
    bool valid = row < Nn;
    const uint4* xr4 = (const uint4*)((const unsigned int*)X + (size_t)row * 128);
    // 1) all 8 A-chunk loads issued upfront (independent)
    uint4 xa[8];
#pragma unroll
    for (int kk = 0; kk < 8; ++kk) {
        int k0 = kk * 32 + q * 8;
        xa[kk] = valid ? xr4[k0 >> 3] : make_uint4(0, 0, 0, 0);
    }
    // 2) transform all fragments: norm + fast ELU + pack
    union { short8 s; unsigned int u[4]; } af[8];
#pragma unroll
    for (int kk = 0; kk < 8; ++kk) {
        int k0 = kk * 32 + q * 8;
        float2 x01 = unpack_bf2(xa[kk].x);
        float2 x23 = unpack_bf2(xa[kk].y);
        float2 x45 = unpack_bf2(xa[kk].z);
        float2 x67 = unpack_bf2(xa[kk].w);
        float4 a0 = *(const float4*)(AB + k0);
        float4 a1 = *(const float4*)(AB + k0 + 4);
        float4 b0 = *(const float4*)(AB + 256 + k0);
        float4 b1 = *(const float4*)(AB + 256 + k0 + 4);
        float v0 = elu_fast(fmaf(a0.x, x01.x, b0.x));
        float v1 = elu_fast(fmaf(a0.y, x01.y, b0.y));
        float v2 = elu_fast(fmaf(a0.z, x23.x, b0.z));
        float v3 = elu_fast(fmaf(a0.w, x23.y, b0.w));
        float v4 = elu_fast(fmaf(a1.x, x45.x, b1.x));
        float v5 = elu_fast(fmaf(a1.y, x45.y, b1.y));
        float v6 = elu_fast(fmaf(a1.z, x67.x, b1.z));
        float v7 = elu_fast(fmaf(a1.w, x67.y, b1.w));
        af[kk].u[0] = pack_bf2(v0, v1);
        af[kk].u[1] = pack_bf2(v2, v3);
        af[kk].u[2] = pack_bf2(v4, v5);
        af[kk].u[3] = pack_bf2(v6, v7);
    }
    // 3) MFMA loop — only L2 Bfrag loads inside, A-fragments all ready
    floatx4 acc[8];
#pragma unroll
    for (int c = 0; c < 8; ++c) acc[c] = (floatx4){0.f, 0.f, 0.f, 0.f};
#pragma unroll
    for (int kk = 0; kk < 8; ++kk) {
        const uint4* bp = Bfrag + kk * 64 + lane;
#pragma unroll
        for (int c = 0; c < 8; ++c) {
            union { short8 s; uint4 u; } bf;
            bf.u = bp[c * 8 * 64];
            acc[c] = __builtin_amdgcn_mfma_f32_16x16x32_bf16(af[kk].s, bf.s, acc[c], 0, 0, 0);
        }
    }
    float a_s[8], a_d[8];
#pragma unroll
    for (int c = 0; c < 8; ++c) {
        a_s[c] = as2[c * 16 + m];
        a_d[c] = ad2[c * 16 + m];
    }
#pragma unroll
    for (int r = 0; r < 4; ++r) {
        int orow = rowbase + q * 4 + r;
        bool vr = orow < Nn;
        ushort us[8];
        float s0 = 0.f, s1 = 0.f, d0 = 0.f, d1 = 0.f;
#pragma unroll
        for (int c = 0; c < 8; ++c) {
            us[c] = f2bf(acc[c][r]);
            float v = bf2f(us[c]);
            if (c < 4) {
                s0 = fmaf(v, a_s[c], s0);
                d0 = fmaf(v, a_d[c], d0);
            } else {
                s1 = fmaf(v, a_s[c], s1);
                d1 = fmaf(v, a_d[c], d1);
            }
        }
#pragma unroll
        for (int o = 1; o < 16; o <<= 1) {
            s0 += __shfl_xor(s0, o);
            s1 += __shfl_xor(s1, o);
            d0 += __shfl_xor(d0, o);
            d1 += __shfl_xor(d1, o);
        }
        if (vr) {
            ushort* op = H2 + (size_t)orow * 128 + m;
#pragma unroll
            for (int c = 0; c < 8; ++c) op[c * 16] = us[c];
            if (m == 0) {
                *(float2*)(al_s + 2 * (size_t)orow) = make_float2(s0, s1);
                *(float2*)(al_d + 2 * (size_t)orow) = make_float2(d0, d1);
            }
        }
    }
}

// ---------------- classifier with fused GraphNorm+ELU, bf16 input ----------------
__global__ __launch_bounds__(256) void k_cls(const ushort* __restrict__ X,
                                             const float* __restrict__ AB,
                                             const float* __restrict__ Wc,
                                             const float* __restrict__ bc,
                                             float* __restrict__ out, int Nn) {
    __shared__ __align__(16) float ls[16 * 132];
    __shared__ __align__(16) float wT[13 * 132];
    __shared__ float bS[13];
    int t = threadIdx.x;
    int n0 = blockIdx.x * 16;
    for (int i = t; i < 128 * 13; i += 256) {
        int k = i / 13, j = i - k * 13;
        wT[j * 132 + k] = Wc[i];
    }
    if (t < 13) bS[t] = bc[t];
    const unsigned int* xu = (const unsigned int*)X;
    for (int idx = t; idx < 16 * 64; idx += 256) {
        int r = idx >> 6, ku = idx & 63;
        int row = n0 + r;
        float vx = 0.f, vy = 0.f;
        if (row < Nn) {
            float2 v = unpack_bf2(xu[(size_t)row * 64 + ku]);
            int k = 2 * ku;
            vx = elu_fast(fmaf(AB[k], v.x, AB[128 + k]));
            vy = elu_fast(fmaf(AB[k + 1], v.y, AB[128 + k + 1]));
        }
        ls[r * 132 + 2 * ku] = vx;
        ls[r * 132 + 2 * ku + 1] = vy;
    }
    __syncthreads();
    if (t < 208) {
        int r = t / 13, j = t - r * 13;
        int row = n0 + r;
        if (row < Nn) {
            float acc = bS[j];
            const float* lr = &ls[r * 132];
            const float* wr = &wT[j * 132];
#pragma unroll 8
            for (int k = 0; k < 128; k += 4) {
                float4 a = *(const float4*)&lr[k];
                float4 b = *(const float4*)&wr[k];
                acc = fmaf(a.x, b.x, fmaf(a.y, b.y, fmaf(a.z, b.z, fmaf(a.w, b.w, acc))));
            }
            out[(size_t)row * 13 + j] = acc;
        }
    }
}

extern "C" void kernel_launch(void* const* d_in, const int* in_sizes, int n_in, void* d_out,
                              int out_size, void* d_ws, size_t ws_size, hipStream_t stream) {
    const float* x = (const float*)d_in[0];
    const int* edge_index = (const int*)d_in[1];
    const float* edge_attr = (const float*)d_in[2];
    const float* W1 = (const float*)d_in[3];
    const float* We1 = (const float*)d_in[4];
    const float* as1 = (const float*)d_in[5];
    const float* ad1 = (const float*)d_in[6];
    const float* ae1 = (const float*)d_in[7];
    const float* b1 = (const float*)d_in[8];
    const float* gn1_w = (const float*)d_in[9];
    const float* gn1_b = (const float*)d_in[10];
    const float* gn1_ms = (const float*)d_in[11];
    const float* W2 = (const float*)d_in[12];
    const float* We2 = (const float*)d_in[13];
    const float* as2 = (const float*)d_in[14];
    const float* ad2 = (const float*)d_in[15];
    const float* ae2 = (const float*)d_in[16];
    const float* b2 = (const float*)d_in[17];
    const float* gn2_w = (const float*)d_in[18];
    const float* gn2_b = (const float*)d_in[19];
    const float* gn2_ms = (const float*)d_in[20];
    const float* Wc = (const float*)d_in[21];
    const float* bc = (const float*)d_in[22];

    const int N = in_sizes[0] / 3;
    const int E = in_sizes[1] / 2;
    const int* srcv = edge_index;
    const int* dstv = edge_index + E;

    // ---- workspace carve (256B-aligned, byte-based) ----
    char* w = (char*)d_ws;
    auto carveB = [&](size_t bytes) -> void* {
        void* p = (void*)w;
        w += ((bytes + 255) / 256) * 256;
        return p;
    };
    // zeroed region first:
    int* deg = (int*)carveB((size_t)N * 4);
    int* cursor = (int*)carveB((size_t)N * 4);
    float* ea_sum = (float*)carveB(8);
    float* statsA = (float*)carveB(512 * 4);
    float* statsB = (float*)carveB(256 * 4);
    char* zero_end = w;
    // not zeroed:
    int* row_ptr = (int*)carveB((size_t)(N + 1) * 4);
    int* bsum = (int*)carveB(1024 * 4);
    int* si = (int*)carveB((size_t)E * 4);
    int* dstc = (int*)carveB((size_t)E * 4);
    float2* eacsr = (float2*)carveB((size_t)E * 8);
    uint4* wmp = (uint4*)carveB((size_t)E * 16);
    float4* wm2 = (float4*)wmp;  // layer-2 weights reuse (wmp dead after agg1)
    float* C1 = (float*)carveB(8 * 4);
    float* lE1 = (float*)carveB(4 * 4);
    float* C2 = (float*)carveB(4 * 4);
    float* lE2 = (float*)carveB(2 * 4);
    float* AB1 = (float*)carveB(512 * 4);
    float* AB2 = (float*)carveB(256 * 4);
    uint4* Bfrag = (uint4*)carveB(4096 * 16);
    float* al_s1 = (float*)carveB((size_t)N * 4 * 4);
    float* al_d1 = (float*)carveB((size_t)N * 4 * 4);
    float* al_s2 = (float*)carveB((size_t)N * 2 * 4);
    float* al_d2 = (float*)carveB((size_t)N * 2 * 4);
    ushort* h1b = (ushort*)carveB((size_t)N * 256 * 2);   // bf16 h1; later aliased by out2b
    ushort* h2b = (ushort*)carveB((size_t)N * 128 * 2);   // bf16 h2
    ushort* out1b = (ushort*)carveB((size_t)N * 256 * 2); // bf16 layer-1 output
    ushort* out2b = h1b;                                  // bf16 layer-2 output (h1b dead)

    hipMemsetAsync(deg, 0, (size_t)(zero_end - (char*)deg), stream);

    const int nb1 = (N + 1023) / 1024;
    const int ebl = (E + 255) / 256;

    k_ea_deg<<<256, 256, 0, stream>>>(edge_attr, dstv, ea_sum, deg, E);
    k_scan1<<<nb1, 1024, 0, stream>>>(deg, row_ptr, bsum, N);
    k_scan23<<<nb1, 1024, 0, stream>>>(row_ptr, bsum, N);
    k_w2frag<<<17, 256, 0, stream>>>(W2, Bfrag, We1, ae1, We2, ae2, ea_sum, E, C1, lE1, C2, lE2);

    // ---- layer 1 ----
    k_l1<<<(N + 1) / 2, 256, 0, stream>>>(x, W1, as1, ad1, h1b, al_s1, al_d1, N);
    k_scatfill<<<ebl, 256, 0, stream>>>(dstv, srcv, edge_attr, row_ptr, cursor, al_s1, al_d1, C1,
                                        si, dstc, eacsr, wmp, E);
    k_agg1<<<(N + 3) / 4, 256, 0, stream>>>(h1b, row_ptr, wmp, al_s1, al_d1, lE1, b1, out1b, N);
    k_stats_bf<32><<<256, 256, 0, stream>>>(out1b, statsA, N);
    k_coef<<<1, 256, 0, stream>>>(statsA, gn1_w, gn1_b, gn1_ms, AB1, N);

    // ---- layer 2 (norm+ELU fused into MFMA GEMM A-load; attn dots fused in epilogue) ----
    k_gemm2_mfma<<<(N + 63) / 64, 256, 0, stream>>>(out1b, AB1, Bfrag, as2, ad2, h2b, al_s2,
                                                    al_d2, N);
    k_fill2<<<ebl, 256, 0, stream>>>(si, dstc, eacsr, al_s2, al_d2, C2, wm2, E);
    k_agg2<<<(N + 3) / 4, 256, 0, stream>>>(h2b, row_ptr, wm2, al_s2, al_d2, lE2, b2, out2b, N);
    k_stats_bf<16><<<256, 256, 0, stream>>>(out2b, statsB, N);
    k_coef<<<1, 128, 0, stream>>>(statsB, gn2_w, gn2_b, gn2_ms, AB2, N);

    // ---- classifier (norm+ELU fused) ----
    k_cls<<<(N + 15) / 16, 256, 0, stream>>>(out2b, AB2, Wc, bc, (float*)d_out, N);
}

// Round 14
// 334.131 us; speedup vs baseline: 1.0852x; 1.0107x over previous
//
#include <hip/hip_runtime.h>
#include <math.h>

#define NEG_SLOPE 0.2f
#define GEPS 1e-5f

typedef __attribute__((ext_vector_type(8))) short short8;
typedef __attribute__((ext_vector_type(4))) float floatx4;

__device__ __forceinline__ float wave_reduce_sum(float v) {
#pragma unroll
    for (int o = 32; o > 0; o >>= 1) v += __shfl_down(v, o);
    return v;
}

__device__ __forceinline__ ushort f2bf(float f) {
    union { float f; unsigned int i; } c;
    c.f = f;
    unsigned int b = c.i;
    b += 0x7fffu + ((b >> 16) & 1u);
    return (ushort)(b >> 16);
}

__device__ __forceinline__ float bf2f(ushort u) {
    union { unsigned int i; float f; } c;
    c.i = (unsigned int)u << 16;
    return c.f;
}

__device__ __forceinline__ float2 unpack_bf2(unsigned int u) {
    union { unsigned int i; float f; } a, b;
    a.i = u << 16;            // low ushort -> even col
    b.i = u & 0xffff0000u;    // high ushort -> odd col
    return make_float2(a.f, b.f);
}

__device__ __forceinline__ unsigned int pack_bf2(float lo, float hi) {
    return (unsigned int)f2bf(lo) | ((unsigned int)f2bf(hi) << 16);
}

__device__ __forceinline__ float lrelu(float v) {
    return (v > 0.f) ? v : v * NEG_SLOPE;
}

__device__ __forceinline__ float elu_fast(float v) {
    return (v > 0.f) ? v : (__expf(v) - 1.f);
}

// ---------------- edge_attr column sums + degree count (merged) ----------------
__global__ void k_ea_deg(const float* __restrict__ ea, const int* __restrict__ dst,
                         float* __restrict__ ea_sum, int* __restrict__ deg, int E) {
    const float2* ea2 = (const float2*)ea;
    float s0 = 0.f, s1 = 0.f;
    int stride = gridDim.x * blockDim.x;
    for (int e = blockIdx.x * blockDim.x + threadIdx.x; e < E; e += stride) {
        float2 v = ea2[e];
        s0 += v.x; s1 += v.y;
        atomicAdd(&deg[dst[e]], 1);
    }
    s0 = wave_reduce_sum(s0);
    s1 = wave_reduce_sum(s1);
    if ((threadIdx.x & 63) == 0) {
        atomicAdd(&ea_sum[0], s0);
        atomicAdd(&ea_sum[1], s1);
    }
}

// ---------------- CSR row_ptr scan (block-local) ----------------
__global__ void k_scan1(const int* __restrict__ deg, int* __restrict__ row_ptr,
                        int* __restrict__ bsum, int N) {
    __shared__ int tmp[1024];
    int tid = threadIdx.x;
    int i = blockIdx.x * 1024 + tid;
    int v = (i < N) ? deg[i] : 0;
    tmp[tid] = v;
    __syncthreads();
#pragma unroll
    for (int off = 1; off < 1024; off <<= 1) {
        int t = (tid >= off) ? tmp[tid - off] : 0;
        __syncthreads();
        tmp[tid] += t;
        __syncthreads();
    }
    if (i < N) row_ptr[i + 1] = tmp[tid];
    if (tid == 1023) bsum[blockIdx.x] = tmp[1023];
}

// block prefix recomputed per block in one wave (nb1 <= 64), then applied
__global__ void k_scan23(int* __restrict__ row_ptr, const int* __restrict__ bsum, int N) {
    __shared__ int off_s;
    int t = threadIdx.x;
    if (t < 64) {
        int v = (t < blockIdx.x) ? bsum[t] : 0;
#pragma unroll
        for (int o = 32; o > 0; o >>= 1) v += __shfl_xor(v, o);
        if (t == 0) off_s = v;
    }
    __syncthreads();
    int off = off_s;
    int i = blockIdx.x * 1024 + t;
    if (i == 0) row_ptr[0] = 0;
    if (i < N) row_ptr[i + 1] += off;
}

// ---------------- W2 -> bf16 MFMA B-fragment layout, + attn consts (block 16) ----------------
__global__ void k_w2frag(const float* __restrict__ W2, uint4* __restrict__ Bfrag,
                         const float* __restrict__ We1, const float* __restrict__ ae1,
                         const float* __restrict__ We2, const float* __restrict__ ae2,
                         const float* __restrict__ ea_sum, int E,
                         float* __restrict__ C1, float* __restrict__ lE1,
                         float* __restrict__ C2, float* __restrict__ lE2) {
    if (blockIdx.x == 16) {
        int t = threadIdx.x, h = t >> 6, lane = t & 63;
        float p0 = We1[t] * ae1[t];
        float p1 = We1[256 + t] * ae1[t];
        p0 = wave_reduce_sum(p0);
        p1 = wave_reduce_sum(p1);
        if (lane == 0) { C1[h] = p0; C1[4 + h] = p1; }
        if (t < 128) {
            float q0 = We2[t] * ae2[t];
            float q1 = We2[128 + t] * ae2[t];
            q0 = wave_reduce_sum(q0);
            q1 = wave_reduce_sum(q1);
            if (lane == 0) { C2[h] = q0; C2[2 + h] = q1; }
        }
        __syncthreads();
        float m0 = ea_sum[0] / (float)E, m1 = ea_sum[1] / (float)E;
        if (t < 4) lE1[t] = m0 * C1[t] + m1 * C1[4 + t];
        if (t < 2) lE2[t] = m0 * C2[t] + m1 * C2[2 + t];
        return;
    }
    int t = blockIdx.x * 256 + threadIdx.x;  // 4096 threads
    int c = t >> 9, kk = (t >> 6) & 7, L = t & 63;
    int q = L >> 4, n = c * 16 + (L & 15);
    int k0 = kk * 32 + q * 8;
    unsigned int u0 = pack_bf2(W2[(k0 + 0) * 128 + n], W2[(k0 + 1) * 128 + n]);
    unsigned int u1 = pack_bf2(W2[(k0 + 2) * 128 + n], W2[(k0 + 3) * 128 + n]);
    unsigned int u2 = pack_bf2(W2[(k0 + 4) * 128 + n], W2[(k0 + 5) * 128 + n]);
    unsigned int u3 = pack_bf2(W2[(k0 + 6) * 128 + n], W2[(k0 + 7) * 128 + n]);
    Bfrag[t] = make_uint4(u0, u1, u2, u3);
}

// ---------------- layer-1 transform: 2 nodes per 256-thread block ----------------
__global__ __launch_bounds__(256) void k_l1(const float* __restrict__ x,
                                            const float* __restrict__ W1,
                                            const float* __restrict__ as1,
                                            const float* __restrict__ ad1,
                                            ushort* __restrict__ h1, float* __restrict__ al_s,
                                            float* __restrict__ al_d, int N) {
    int u = threadIdx.x >> 7;
    int n = blockIdx.x * 2 + u;
    if (n >= N) return;
    int t = threadIdx.x & 127, lane = threadIdx.x & 63;
    int c0 = 2 * t;
    float x0 = x[3 * n], x1 = x[3 * n + 1], x2 = x[3 * n + 2];
    float h0 = fmaf(x0, W1[c0], fmaf(x1, W1[256 + c0], x2 * W1[512 + c0]));
    float h1v = fmaf(x0, W1[c0 + 1], fmaf(x1, W1[257 + c0], x2 * W1[513 + c0]));
    ((unsigned int*)h1)[(size_t)n * 128 + t] = pack_bf2(h0, h1v);
    float ps = h0 * as1[c0] + h1v * as1[c0 + 1];
    float pd = h0 * ad1[c0] + h1v * ad1[c0 + 1];
#pragma unroll
    for (int o = 16; o > 0; o >>= 1) {
        ps += __shfl_xor(ps, o);
        pd += __shfl_xor(pd, o);
    }
    if ((lane & 31) == 0) {
        int h = c0 >> 6;
        al_s[n * 4 + h] = ps;
        al_d[n * 4 + h] = pd;
    }
}

// ---------------- CSR scatter fused with layer-1 edge-weight computation ----------------
__global__ void k_scatfill(const int* __restrict__ dst, const int* __restrict__ src,
                           const float* __restrict__ ea, const int* __restrict__ row_ptr,
                           int* __restrict__ cursor, const float* __restrict__ al_s1,
                           const float* __restrict__ al_d1, const float* __restrict__ C1,
                           int* __restrict__ si, int* __restrict__ dstc,
                           float2* __restrict__ eacsr, uint4* __restrict__ wmp, int E) {
    int e = blockIdx.x * 256 + threadIdx.x;
    if (e >= E) return;
    int d = dst[e];
    int pos = atomicAdd(&cursor[d], 1);
    int slot = row_ptr[d] + pos;
    int s = src[e];
    float2 v = ((const float2*)ea)[e];
    float4 as = *(const float4*)(al_s1 + 4 * (size_t)s);
    float4 ad = *(const float4*)(al_d1 + 4 * (size_t)d);
    float w0 = __expf(lrelu(as.x + ad.x + v.x * C1[0] + v.y * C1[4]));
    float w1 = __expf(lrelu(as.y + ad.y + v.x * C1[1] + v.y * C1[5]));
    float w2 = __expf(lrelu(as.z + ad.z + v.x * C1[2] + v.y * C1[6]));
    float w3 = __expf(lrelu(as.w + ad.w + v.x * C1[3] + v.y * C1[7]));
    si[slot] = s;
    dstc[slot] = d;
    eacsr[slot] = v;
    wmp[slot] = make_uint4((unsigned int)s, pack_bf2(w0, w1), pack_bf2(w2, w3), 0u);
}

// ---------------- layer-2 edge-weight fill (CSR order) ----------------
__global__ void k_fill2(const int* __restrict__ si, const int* __restrict__ dstc,
                        const float2* __restrict__ eacsr, const float* __restrict__ al_s2,
                        const float* __restrict__ al_d2, const float* __restrict__ C2,
                        float4* __restrict__ wm2, int E) {
    int e = blockIdx.x * 256 + threadIdx.x;
    if (e >= E) return;
    int s = si[e], d = dstc[e];
    float2 v = eacsr[e];
    float2 as = *(const float2*)(al_s2 + 2 * (size_t)s);
    float2 ad = *(const float2*)(al_d2 + 2 * (size_t)d);
    float wA = __expf(lrelu(as.x + ad.x + v.x * C2[0] + v.y * C2[2]));
    float wB = __expf(lrelu(as.y + ad.y + v.x * C2[1] + v.y * C2[3]));
    wm2[e] = make_float4(__int_as_float(s), wA, wB, 0.f);
}

// ---------------- layer-1 aggregation: one wave per node, full 512B row ----------------
__global__ __launch_bounds__(256) void k_agg1(const ushort* __restrict__ h1,
                                              const int* __restrict__ row_ptr,
                                              const uint4* __restrict__ wmp,
                                              const float* __restrict__ al_s,
                                              const float* __restrict__ al_d,
                                              const float* __restrict__ lE,
                                              const float* __restrict__ bias,
                                              ushort* __restrict__ out, int N) {
    int n = blockIdx.x * 4 + (threadIdx.x >> 6);
    if (n >= N) return;
    int lane = threadIdx.x & 63;
    int g = lane >> 5, c32 = lane & 31;
    int h = c32 >> 3;
    const uint4* h1u4 = (const uint4*)h1;
    float4 as = *(const float4*)(al_s + 4 * (size_t)n);
    float4 ad = *(const float4*)(al_d + 4 * (size_t)n);
    float4 le = *(const float4*)lE;
    float ws0 = __expf(lrelu(as.x + ad.x + le.x));
    float ws1 = __expf(lrelu(as.y + ad.y + le.y));
    float ws2 = __expf(lrelu(as.z + ad.z + le.z));
    float ws3 = __expf(lrelu(as.w + ad.w + le.w));
    float wsh = (h == 0) ? ws0 : (h == 1) ? ws1 : (h == 2) ? ws2 : ws3;
    uint4 hs = h1u4[(size_t)n * 32 + c32];
    float wself = (g == 0) ? wsh : 0.f;
    float dsum = wself;
    float acc[8];
    {
        float2 t0 = unpack_bf2(hs.x), t1 = unpack_bf2(hs.y);
        float2 t2 = unpack_bf2(hs.z), t3 = unpack_bf2(hs.w);
        acc[0] = wself * t0.x; acc[1] = wself * t0.y;
        acc[2] = wself * t1.x; acc[3] = wself * t1.y;
        acc[4] = wself * t2.x; acc[5] = wself * t2.y;
        acc[6] = wself * t3.x; acc[7] = wself * t3.y;
    }
    int i0 = row_ptr[n];
    int cnt = row_ptr[n + 1] - i0;
    if (cnt > 0) {
        int last = cnt - 1;
        int j0 = g; float m0 = 1.f;
        if (j0 > last) { j0 = last; m0 = 0.f; }
        int j1 = 2 + g; float m1 = 1.f;
        if (j1 > last) { j1 = last; m1 = 0.f; }
        uint4 meA = wmp[i0 + j0];
        uint4 gvA = h1u4[(size_t)meA.x * 32 + c32];
        uint4 meB = wmp[i0 + j1];
        float mkA = m0, mkB = m1;
        int nit = (cnt + 1) >> 1;
        for (int it = 1; it < nit; ++it) {
            uint4 gvB = h1u4[(size_t)meB.x * 32 + c32];
            int jn = 2 * (it + 1) + g;
            float mn = 1.f;
            if (jn > last) { jn = last; mn = 0.f; }
            uint4 meC = wmp[i0 + jn];
            float2 w01 = unpack_bf2(meA.y);
            float2 w23 = unpack_bf2(meA.z);
            float2 wp = (h < 2) ? w01 : w23;
            float wg = ((h & 1) ? wp.y : wp.x) * mkA;
            dsum += wg;
            float2 u;
            u = unpack_bf2(gvA.x); acc[0] = fmaf(wg, u.x, acc[0]); acc[1] = fmaf(wg, u.y, acc[1]);
            u = unpack_bf2(gvA.y); acc[2] = fmaf(wg, u.x, acc[2]); acc[3] = fmaf(wg, u.y, acc[3]);
            u = unpack_bf2(gvA.z); acc[4] = fmaf(wg, u.x, acc[4]); acc[5] = fmaf(wg, u.y, acc[5]);
            u = unpack_bf2(gvA.w); acc[6] = fmaf(wg, u.x, acc[6]); acc[7] = fmaf(wg, u.y, acc[7]);
            meA = meB; gvA = gvB; meB = meC; mkA = mkB; mkB = mn;
        }
        float2 w01 = unpack_bf2(meA.y);
        float2 w23 = unpack_bf2(meA.z);
        float2 wp = (h < 2) ? w01 : w23;
        float wg = ((h & 1) ? wp.y : wp.x) * mkA;
        dsum += wg;
        float2 u;
        u = unpack_bf2(gvA.x); acc[0] = fmaf(wg, u.x, acc[0]); acc[1] = fmaf(wg, u.y, acc[1]);
        u = unpack_bf2(gvA.y); acc[2] = fmaf(wg, u.x, acc[2]); acc[3] = fmaf(wg, u.y, acc[3]);
        u = unpack_bf2(gvA.z); acc[4] = fmaf(wg, u.x, acc[4]); acc[5] = fmaf(wg, u.y, acc[5]);
        u = unpack_bf2(gvA.w); acc[6] = fmaf(wg, u.x, acc[6]); acc[7] = fmaf(wg, u.y, acc[7]);
    }
#pragma unroll
    for (int k = 0; k < 8; ++k) acc[k] += __shfl_xor(acc[k], 32);
    dsum += __shfl_xor(dsum, 32);
    if (g == 0) {
        float inv = 1.f / dsum;
        const float* bp = bias + c32 * 8;
        float4 b0 = *(const float4*)bp;
        float4 b1 = *(const float4*)(bp + 4);
        uint4 o;
        o.x = pack_bf2(fmaf(acc[0], inv, b0.x), fmaf(acc[1], inv, b0.y));
        o.y = pack_bf2(fmaf(acc[2], inv, b0.z), fmaf(acc[3], inv, b0.w));
        o.z = pack_bf2(fmaf(acc[4], inv, b1.x), fmaf(acc[5], inv, b1.y));
        o.w = pack_bf2(fmaf(acc[6], inv, b1.z), fmaf(acc[7], inv, b1.w));
        ((uint4*)out)[(size_t)n * 32 + c32] = o;
    }
}

// ---------------- layer-2 aggregation: 1 wave/node, 4 groups x 16 col-chunks ----------------
__global__ __launch_bounds__(256) void k_agg2(const ushort* __restrict__ h2,
                                              const int* __restrict__ row_ptr,
                                              const float4* __restrict__ wm,
                                              const float* __restrict__ al_s,
                                              const float* __restrict__ al_d,
                                              const float* __restrict__ lE,
                                              const float* __restrict__ bias,
                                              ushort* __restrict__ out, int N) {
    int n = blockIdx.x * 4 + (threadIdx.x >> 6);
    if (n >= N) return;
    int lane = threadIdx.x & 63;
    int g = lane >> 4, c16 = lane & 15;
    bool hi = c16 >= 8;
    const uint4* h2u4 = (const uint4*)h2;
    float2 ad = *(const float2*)(al_d + 2 * (size_t)n);
    float2 as = *(const float2*)(al_s + 2 * (size_t)n);
    float wsA = __expf(lrelu(as.x + ad.x + lE[0]));
    float wsB = __expf(lrelu(as.y + ad.y + lE[1]));
    uint4 hs = h2u4[(size_t)n * 16 + c16];
    float wself = (g == 0) ? (hi ? wsB : wsA) : 0.f;
    float dsum = wself;
    float acc[8];
    {
        float2 t0 = unpack_bf2(hs.x), t1 = unpack_bf2(hs.y);
        float2 t2 = unpack_bf2(hs.z), t3 = unpack_bf2(hs.w);
        acc[0] = wself * t0.x; acc[1] = wself * t0.y;
        acc[2] = wself * t1.x; acc[3] = wself * t1.y;
        acc[4] = wself * t2.x; acc[5] = wself * t2.y;
        acc[6] = wself * t3.x; acc[7] = wself * t3.y;
    }
    int i0 = row_ptr[n];
    int cnt = row_ptr[n + 1] - i0;
    if (cnt > 0) {
        int last = cnt - 1;
        int j0 = g; float m0 = 1.f;
        if (j0 > last) { j0 = last; m0 = 0.f; }
        int j1 = 4 + g; float m1 = 1.f;
        if (j1 > last) { j1 = last; m1 = 0.f; }
        float4 meA = wm[i0 + j0];
        uint4 gvA = h2u4[(size_t)__float_as_int(meA.x) * 16 + c16];
        float4 meB = wm[i0 + j1];
        float mkA = m0, mkB = m1;
        int nit = (cnt + 3) >> 2;
        for (int it = 1; it < nit; ++it) {
            uint4 gvB = h2u4[(size_t)__float_as_int(meB.x) * 16 + c16];
            int jn = 4 * (it + 1) + g;
            float mn = 1.f;
            if (jn > last) { jn = last; mn = 0.f; }
            float4 meC = wm[i0 + jn];
            float wg = (hi ? meA.z : meA.y) * mkA;
            dsum += wg;
            float2 u;
            u = unpack_bf2(gvA.x); acc[0] = fmaf(wg, u.x, acc[0]); acc[1] = fmaf(wg, u.y, acc[1]);
            u = unpack_bf2(gvA.y); acc[2] = fmaf(wg, u.x, acc[2]); acc[3] = fmaf(wg, u.y, acc[3]);
            u = unpack_bf2(gvA.z); acc[4] = fmaf(wg, u.x, acc[4]); acc[5] = fmaf(wg, u.y, acc[5]);
            u = unpack_bf2(gvA.w); acc[6] = fmaf(wg, u.x, acc[6]); acc[7] = fmaf(wg, u.y, acc[7]);
            meA = meB; gvA = gvB; meB = meC; mkA = mkB; mkB = mn;
        }
        float wg = (hi ? meA.z : meA.y) * mkA;
        dsum += wg;
        float2 u;
        u = unpack_bf2(gvA.x); acc[0] = fmaf(wg, u.x, acc[0]); acc[1] = fmaf(wg, u.y, acc[1]);
        u = unpack_bf2(gvA.y); acc[2] = fmaf(wg, u.x, acc[2]); acc[3] = fmaf(wg, u.y, acc[3]);
        u = unpack_bf2(gvA.z); acc[4] = fmaf(wg, u.x, acc[4]); acc[5] = fmaf(wg, u.y, acc[5]);
        u = unpack_bf2(gvA.w); acc[6] = fmaf(wg, u.x, acc[6]); acc[7] = fmaf(wg, u.y, acc[7]);
    }
#pragma unroll
    for (int k = 0; k < 8; ++k) {
        acc[k] += __shfl_xor(acc[k], 16);
        acc[k] += __shfl_xor(acc[k], 32);
    }
    dsum += __shfl_xor(dsum, 16);
    dsum += __shfl_xor(dsum, 32);
    if (g == 0) {
        float inv = 1.f / dsum;
        const float* bp = bias + c16 * 8;
        float4 b0 = *(const float4*)bp;
        float4 b1 = *(const float4*)(bp + 4);
        uint4 o;
        o.x = pack_bf2(fmaf(acc[0], inv, b0.x), fmaf(acc[1], inv, b0.y));
        o.y = pack_bf2(fmaf(acc[2], inv, b0.z), fmaf(acc[3], inv, b0.w));
        o.z = pack_bf2(fmaf(acc[4], inv, b1.x), fmaf(acc[5], inv, b1.y));
        o.w = pack_bf2(fmaf(acc[6], inv, b1.z), fmaf(acc[7], inv, b1.w));
        ((uint4*)out)[(size_t)n * 16 + c16] = o;
    }
}

// ---------------- GraphNorm column stats: uint4 streaming + LDS tree + few atomics ----------
template <int C4>
__global__ __launch_bounds__(256) void k_stats_bf(const ushort* __restrict__ x,
                                                  float* __restrict__ stats, int rows) {
    const int C = C4 * 8;
    const int RG = 256 / C4;
    int t = threadIdx.x;
    int c = t & (C4 - 1);
    int rg = t / C4;
    int rpb = (rows + gridDim.x - 1) / gridDim.x;
    int r0 = blockIdx.x * rpb;
    int r1 = r0 + rpb;
    if (r1 > rows) r1 = rows;
    const uint4* xu = (const uint4*)x;
    float s[8] = {0.f, 0.f, 0.f, 0.f, 0.f, 0.f, 0.f, 0.f};
    float q[8] = {0.f, 0.f, 0.f, 0.f, 0.f, 0.f, 0.f, 0.f};
    for (int r = r0 + rg; r < r1; r += RG) {
        uint4 v = xu[(size_t)r * C4 + c];
        float2 a0 = unpack_bf2(v.x), a1 = unpack_bf2(v.y);
        float2 a2 = unpack_bf2(v.z), a3 = unpack_bf2(v.w);
        s[0] += a0.x; q[0] = fmaf(a0.x, a0.x, q[0]);
        s[1] += a0.y; q[1] = fmaf(a0.y, a0.y, q[1]);
        s[2] += a1.x; q[2] = fmaf(a1.x, a1.x, q[2]);
        s[3] += a1.y; q[3] = fmaf(a1.y, a1.y, q[3]);
        s[4] += a2.x; q[4] = fmaf(a2.x, a2.x, q[4]);
        s[5] += a2.y; q[5] = fmaf(a2.y, a2.y, q[5]);
        s[6] += a3.x; q[6] = fmaf(a3.x, a3.x, q[6]);
        s[7] += a3.y; q[7] = fmaf(a3.y, a3.y, q[7]);
    }
    __shared__ float ls[256 * 16];
#pragma unroll
    for (int k = 0; k < 8; ++k) {
        ls[t * 16 + k] = s[k];
        ls[t * 16 + 8 + k] = q[k];
    }
    __syncthreads();
    if (t < C) {
        int cc = t >> 3, k = t & 7;
        float ssum = 0.f, qsum = 0.f;
#pragma unroll
        for (int g = 0; g < RG; ++g) {
            ssum += ls[(g * C4 + cc) * 16 + k];
            qsum += ls[(g * C4 + cc) * 16 + 8 + k];
        }
        atomicAdd(&stats[t], ssum);
        atomicAdd(&stats[C + t], qsum);
    }
}

// ---------------- MFMA GEMM2 + per-block coef from stats + fused layer-2 attn dots ----------
__global__ __launch_bounds__(256) void k_gemm2_mfma(const ushort* __restrict__ X,
                                                    const float* __restrict__ stats,
                                                    const float* __restrict__ gw,
                                                    const float* __restrict__ gb,
                                                    const float* __restrict__ gms,
                                                    const uint4* __restrict__ Bfrag,
                                                    const float* __restrict__ as2,
                                                    const float* __restrict__ ad2,
                                                    ushort* __restrict__ H2,
                                                    float* __restrict__ al_s,
                                                    float* __restrict__ al_d, int Nn) {
    __shared__ __align__(16) float ABs[512];
    {
        int t = threadIdx.x;
        float inv = 1.f / (float)Nn;
        float mean = stats[t] * inv;
        float cm = mean * gms[t];
        float var = stats[256 + t] * inv - 2.f * cm * mean + cm * cm;
        float A = gw[t] * rsqrtf(var + GEPS);
        ABs[t] = A;
        ABs[256 + t] = gb[t] - A * cm;
    }
    __syncthreads();
    int wave = threadIdx.x >> 6, lane = threadIdx.x & 63;
    int q = lane >> 4, m = lane & 15;
    int rowbase = blockIdx.x * 64 + wave * 16;
    int row = rowbase + m;
    bool valid = row < Nn;
    const uint4* xr4 = (const uint4*)((const unsigned int*)X + (size_t)row * 128);
    uint4 xa[8];
#pragma unroll
    for (int kk = 0; kk < 8; ++kk) {
        int k0 = kk * 32 + q * 8;
        xa[kk] = valid ? xr4[k0 >> 3] : make_uint4(0, 0, 0, 0);
    }
    union { short8 s; unsigned int u[4]; } af[8];
#pragma unroll
    for (int kk = 0; kk < 8; ++kk) {
        int k0 = kk * 32 + q * 8;
        float2 x01 = unpack_bf2(xa[kk].x);
        float2 x23 = unpack_bf2(xa[kk].y);
        float2 x45 = unpack_bf2(xa[kk].z);
        float2 x67 = unpack_bf2(xa[kk].w);
        float4 a0 = *(const float4*)(ABs + k0);
        float4 a1 = *(const float4*)(ABs + k0 + 4);
        float4 b0 = *(const float4*)(ABs + 256 + k0);
        float4 b1 = *(const float4*)(ABs + 256 + k0 + 4);
        float v0 = elu_fast(fmaf(a0.x, x01.x, b0.x));
        float v1 = elu_fast(fmaf(a0.y, x01.y, b0.y));
        float v2 = elu_fast(fmaf(a0.z, x23.x, b0.z));
        float v3 = elu_fast(fmaf(a0.w, x23.y, b0.w));
        float v4 = elu_fast(fmaf(a1.x, x45.x, b1.x));
        float v5 = elu_fast(fmaf(a1.y, x45.y, b1.y));
        float v6 = elu_fast(fmaf(a1.z, x67.x, b1.z));
        float v7 = elu_fast(fmaf(a1.w, x67.y, b1.w));
        af[kk].u[0] = pack_bf2(v0, v1);
        af[kk].u[1] = pack_bf2(v2, v3);
        af[kk].u[2] = pack_bf2(v4, v5);
        af[kk].u[3] = pack_bf2(v6, v7);
    }
    floatx4 acc[8];
#pragma unroll
    for (int c = 0; c < 8; ++c) acc[c] = (floatx4){0.f, 0.f, 0.f, 0.f};
#pragma unroll
    for (int kk = 0; kk < 8; ++kk) {
        const uint4* bp = Bfrag + kk * 64 + lane;
#pragma unroll
        for (int c = 0; c < 8; ++c) {
            union { short8 s; uint4 u; } bf;
            bf.u = bp[c * 8 * 64];
            acc[c] = __builtin_amdgcn_mfma_f32_16x16x32_bf16(af[kk].s, bf.s, acc[c], 0, 0, 0);
        }
    }
    float a_s[8], a_d[8];
#pragma unroll
    for (int c = 0; c < 8; ++c) {
        a_s[c] = as2[c * 16 + m];
        a_d[c] = ad2[c * 16 + m];
    }
#pragma unroll
    for (int r = 0; r < 4; ++r) {
        int orow = rowbase + q * 4 + r;
        bool vr = orow < Nn;
        ushort us[8];
        float s0 = 0.f, s1 = 0.f, d0 = 0.f, d1 = 0.f;
#pragma unroll
        for (int c = 0; c < 8; ++c) {
            us[c] = f2bf(acc[c][r]);
            float v = bf2f(us[c]);
            if (c < 4) {
                s0 = fmaf(v, a_s[c], s0);
                d0 = fmaf(v, a_d[c], d0);
            } else {
                s1 = fmaf(v, a_s[c], s1);
                d1 = fmaf(v, a_d[c], d1);
            }
        }
#pragma unroll
        for (int o = 1; o < 16; o <<= 1) {
            s0 += __shfl_xor(s0, o);
            s1 += __shfl_xor(s1, o);
            d0 += __shfl_xor(d0, o);
            d1 += __shfl_xor(d1, o);
        }
        if (vr) {
            ushort* op = H2 + (size_t)orow * 128 + m;
#pragma unroll
            for (int c = 0; c < 8; ++c) op[c * 16] = us[c];
            if (m == 0) {
                *(float2*)(al_s + 2 * (size_t)orow) = make_float2(s0, s1);
                *(float2*)(al_d + 2 * (size_t)orow) = make_float2(d0, d1);
            }
        }
    }
}

// ---------------- classifier: per-block coef from stats + fused GraphNorm+ELU ----------------
__global__ __launch_bounds__(256) void k_cls(const ushort* __restrict__ X,
                                             const float* __restrict__ stats,
                                             const float* __restrict__ gw,
                                             const float* __restrict__ gb,
                                             const float* __restrict__ gms,
                                             const float* __restrict__ Wc,
                                             const float* __restrict__ bc,
                                             float* __restrict__ out, int Nn) {
    __shared__ __align__(16) float ls[16 * 132];
    __shared__ __align__(16) float wT[13 * 132];
    __shared__ __align__(16) float ABs[256];
    __shared__ float bS[13];
    int t = threadIdx.x;
    int n0 = blockIdx.x * 16;
    if (t < 128) {
        float inv = 1.f / (float)Nn;
        float mean = stats[t] * inv;
        float cm = mean * gms[t];
        float var = stats[128 + t] * inv - 2.f * cm * mean + cm * cm;
        float A = gw[t] * rsqrtf(var + GEPS);
        ABs[t] = A;
        ABs[128 + t] = gb[t] - A * cm;
    }
    for (int i = t; i < 128 * 13; i += 256) {
        int k = i / 13, j = i - k * 13;
        wT[j * 132 + k] = Wc[i];
    }
    if (t < 13) bS[t] = bc[t];
    __syncthreads();
    const unsigned int* xu = (const unsigned int*)X;
    for (int idx = t; idx < 16 * 64; idx += 256) {
        int r = idx >> 6, ku = idx & 63;
        int row = n0 + r;
        float vx = 0.f, vy = 0.f;
        if (row < Nn) {
            float2 v = unpack_bf2(xu[(size_t)row * 64 + ku]);
            int k = 2 * ku;
            vx = elu_fast(fmaf(ABs[k], v.x, ABs[128 + k]));
            vy = elu_fast(fmaf(ABs[k + 1], v.y, ABs[128 + k + 1]));
        }
        ls[r * 132 + 2 * ku] = vx;
        ls[r * 132 + 2 * ku + 1] = vy;
    }
    __syncthreads();
    if (t < 208) {
        int r = t / 13, j = t - r * 13;
        int row = n0 + r;
        if (row < Nn) {
            float acc = bS[j];
            const float* lr = &ls[r * 132];
            const float* wr = &wT[j * 132];
#pragma unroll 8
            for (int k = 0; k < 128; k += 4) {
                float4 a = *(const float4*)&lr[k];
                float4 b = *(const float4*)&wr[k];
                acc = fmaf(a.x, b.x, fmaf(a.y, b.y, fmaf(a.z, b.z, fmaf(a.w, b.w, acc))));
            }
            out[(size_t)row * 13 + j] = acc;
        }
    }
}

extern "C" void kernel_launch(void* const* d_in, const int* in_sizes, int n_in, void* d_out,
                              int out_size, void* d_ws, size_t ws_size, hipStream_t stream) {
    const float* x = (const float*)d_in[0];
    const int* edge_index = (const int*)d_in[1];
    const float* edge_attr = (const float*)d_in[2];
    const float* W1 = (const float*)d_in[3];
    const float* We1 = (const float*)d_in[4];
    const float* as1 = (const float*)d_in[5];
    const float* ad1 = (const float*)d_in[6];
    const float* ae1 = (const float*)d_in[7];
    const float* b1 = (const float*)d_in[8];
    const float* gn1_w = (const float*)d_in[9];
    const float* gn1_b = (const float*)d_in[10];
    const float* gn1_ms = (const float*)d_in[11];
    const float* W2 = (const float*)d_in[12];
    const float* We2 = (const float*)d_in[13];
    const float* as2 = (const float*)d_in[14];
    const float* ad2 = (const float*)d_in[15];
    const float* ae2 = (const float*)d_in[16];
    const float* b2 = (const float*)d_in[17];
    const float* gn2_w = (const float*)d_in[18];
    const float* gn2_b = (const float*)d_in[19];
    const float* gn2_ms = (const float*)d_in[20];
    const float* Wc = (const float*)d_in[21];
    const float* bc = (const float*)d_in[22];

    const int N = in_sizes[0] / 3;
    const int E = in_sizes[1] / 2;
    const int* srcv = edge_index;
    const int* dstv = edge_index + E;

    // ---- workspace carve (256B-aligned, byte-based) ----
    char* w = (char*)d_ws;
    auto carveB = [&](size_t bytes) -> void* {
        void* p = (void*)w;
        w += ((bytes + 255) / 256) * 256;
        return p;
    };
    // zeroed region first:
    int* deg = (int*)carveB((size_t)N * 4);
    int* cursor = (int*)carveB((size_t)N * 4);
    float* ea_sum = (float*)carveB(8);
    float* statsA = (float*)carveB(512 * 4);
    float* statsB = (float*)carveB(256 * 4);
    char* zero_end = w;
    // not zeroed:
    int* row_ptr = (int*)carveB((size_t)(N + 1) * 4);
    int* bsum = (int*)carveB(1024 * 4);
    int* si = (int*)carveB((size_t)E * 4);
    int* dstc = (int*)carveB((size_t)E * 4);
    float2* eacsr = (float2*)carveB((size_t)E * 8);
    uint4* wmp = (uint4*)carveB((size_t)E * 16);
    float4* wm2 = (float4*)wmp;  // layer-2 weights reuse (wmp dead after agg1)
    float* C1 = (float*)carveB(8 * 4);
    float* lE1 = (float*)carveB(4 * 4);
    float* C2 = (float*)carveB(4 * 4);
    float* lE2 = (float*)carveB(2 * 4);
    uint4* Bfrag = (uint4*)carveB(4096 * 16);
    float* al_s1 = (float*)carveB((size_t)N * 4 * 4);
    float* al_d1 = (float*)carveB((size_t)N * 4 * 4);
    float* al_s2 = (float*)carveB((size_t)N * 2 * 4);
    float* al_d2 = (float*)carveB((size_t)N * 2 * 4);
    ushort* h1b = (ushort*)carveB((size_t)N * 256 * 2);   // bf16 h1; later aliased by out2b
    ushort* h2b = (ushort*)carveB((size_t)N * 128 * 2);   // bf16 h2
    ushort* out1b = (ushort*)carveB((size_t)N * 256 * 2); // bf16 layer-1 output
    ushort* out2b = h1b;                                  // bf16 layer-2 output (h1b dead)

    hipMemsetAsync(deg, 0, (size_t)(zero_end - (char*)deg), stream);

    const int nb1 = (N + 1023) / 1024;
    const int ebl = (E + 255) / 256;

    k_ea_deg<<<256, 256, 0, stream>>>(edge_attr, dstv, ea_sum, deg, E);
    k_scan1<<<nb1, 1024, 0, stream>>>(deg, row_ptr, bsum, N);
    k_scan23<<<nb1, 1024, 0, stream>>>(row_ptr, bsum, N);
    k_w2frag<<<17, 256, 0, stream>>>(W2, Bfrag, We1, ae1, We2, ae2, ea_sum, E, C1, lE1, C2, lE2);

    // ---- layer 1 ----
    k_l1<<<(N + 1) / 2, 256, 0, stream>>>(x, W1, as1, ad1, h1b, al_s1, al_d1, N);
    k_scatfill<<<ebl, 256, 0, stream>>>(dstv, srcv, edge_attr, row_ptr, cursor, al_s1, al_d1, C1,
                                        si, dstc, eacsr, wmp, E);
    k_agg1<<<(N + 3) / 4, 256, 0, stream>>>(h1b, row_ptr, wmp, al_s1, al_d1, lE1, b1, out1b, N);
    k_stats_bf<32><<<256, 256, 0, stream>>>(out1b, statsA, N);

    // ---- layer 2 (norm coef computed per block from stats; attn dots fused in epilogue) ----
    k_gemm2_mfma<<<(N + 63) / 64, 256, 0, stream>>>(out1b, statsA, gn1_w, gn1_b, gn1_ms, Bfrag,
                                                    as2, ad2, h2b, al_s2, al_d2, N);
    k_fill2<<<ebl, 256, 0, stream>>>(si, dstc, eacsr, al_s2, al_d2, C2, wm2, E);
    k_agg2<<<(N + 3) / 4, 256, 0, stream>>>(h2b, row_ptr, wm2, al_s2, al_d2, lE2, b2, out2b, N);
    k_stats_bf<16><<<256, 256, 0, stream>>>(out2b, statsB, N);

    // ---- classifier (norm coef computed per block from stats) ----
    k_cls<<<(N + 15) / 16, 256, 0, stream>>>(out2b, statsB, gn2_w, gn2_b, gn2_ms, Wc, bc,
                                             (float*)d_out, N);
}